// Round 9
// baseline (494.203 us; speedup 1.0000x reference)
//
#include <hip/hip_runtime.h>

typedef __attribute__((ext_vector_type(8))) __bf16 bf16x8;
typedef __attribute__((ext_vector_type(4))) float f32x4;
typedef __attribute__((ext_vector_type(16))) float f32x16;
typedef __attribute__((ext_vector_type(8))) unsigned short u16x8;
typedef __attribute__((ext_vector_type(2))) unsigned uint2v;

__device__ __forceinline__ unsigned short f2bf(float f){
  union { float f; unsigned u; } v; v.f = f;
  unsigned r = v.u + 0x7FFFu + ((v.u >> 16) & 1u);
  return (unsigned short)(r >> 16);
}
__device__ __forceinline__ float bf2f(unsigned short u){
  union { unsigned u; float f; } v; v.u = ((unsigned)u) << 16;
  return v.f;
}

typedef const unsigned __attribute__((address_space(1)))* gas_ptr;
typedef unsigned __attribute__((address_space(3)))* las_ptr;

__device__ __forceinline__ void gload_lds16(const void* g, void* l){
  __builtin_amdgcn_global_load_lds((gas_ptr)g, (las_ptr)l, 16, 0, 0);
}

__device__ __forceinline__ unsigned cvtpk(float lo, float hi){
  unsigned r;
  asm("v_cvt_pk_bf16_f32 %0, %1, %2" : "=v"(r) : "v"(lo), "v"(hi));
  return r;
}
__device__ __forceinline__ void swap32(unsigned &a, unsigned &b){
  uint2v r = __builtin_amdgcn_permlane32_swap(a, b, false, false);
  a = r[0]; b = r[1];
}
__device__ __forceinline__ float xsum32(float v){
  union { float f; unsigned u; } a; a.f = v;
  uint2v r = __builtin_amdgcn_permlane32_swap(a.u, a.u, false, false);
  union { unsigned u; float f; } x, y; x.u = r[0]; y.u = r[1];
  return x.f + y.f;
}

// ---------------- f32 -> bf16 conversion ----------------
__global__ __launch_bounds__(256) void cvt_f32_bf16(const float* __restrict__ in,
                                                    unsigned short* __restrict__ out){
  size_t i = ((size_t)blockIdx.x * 256 + threadIdx.x) * 4;
  float4 vv = *(const float4*)(in + i);
  ushort4 o;
  o.x = f2bf(vv.x); o.y = f2bf(vv.y); o.z = f2bf(vv.z); o.w = f2bf(vv.w);
  *(ushort4*)(out + i) = o;
}
__global__ __launch_bounds__(256) void cvt_w4(const float* __restrict__ w0, const float* __restrict__ w1,
                                              const float* __restrict__ w2, const float* __restrict__ w3,
                                              unsigned short* o0, unsigned short* o1,
                                              unsigned short* o2, unsigned short* o3){
  const float* in = blockIdx.y == 0 ? w0 : blockIdx.y == 1 ? w1 : blockIdx.y == 2 ? w2 : w3;
  unsigned short* out = blockIdx.y == 0 ? o0 : blockIdx.y == 1 ? o1 : blockIdx.y == 2 ? o2 : o3;
  size_t i = ((size_t)blockIdx.x * 256 + threadIdx.x) * 4;
  float4 vv = *(const float4*)(in + i);
  ushort4 o;
  o.x = f2bf(vv.x); o.y = f2bf(vv.y); o.z = f2bf(vv.z); o.w = f2bf(vv.w);
  *(ushort4*)(out + i) = o;
}

// ============ 256x256 GEMM, 32x32x16 MFMA, 4-phase, reg-cached ============
// C[M,N] = A[M,K] * B[N,K]^T. QKV mode: one dispatch computes all three
// projections (bc selects weight/output; RoPE fused for Q,K).
// 24 ds_read_b128 / wave / K-tile; stage schedule and vmcnt(4) boundary as
// verified in R6 (t+1 halves landed, t+2 halves in flight).
#define BUF(op, half, par) (LDS + (((op) * 2 + (half)) * 2 + (par)) * 16384)

#define STAGE(op, gbase, half, par, kt) do {                                   \
  _Pragma("unroll")                                                            \
  for (int c_ = 0; c_ < 2; ++c_){                                              \
    int slot_ = c_ * 512 + w * 64 + l;                                         \
    int row_ = slot_ >> 3, colb_ = slot_ & 7;                                  \
    gload_lds16((const char*)((gbase) + (size_t)((half) * 128 + row_) * K +    \
                              (size_t)(kt) * 64 + ((colb_ ^ (row_ & 7)) * 8)), \
                BUF(op, half, par) + c_ * 8192 + w * 1024);                    \
  } } while (0)

#define RD_A(buf) do {                                                         \
  const char* Ab_ = (buf);                                                     \
  _Pragma("unroll")                                                            \
  for (int m_ = 0; m_ < 2; ++m_){                                              \
    int row_ = wm * 64 + m_ * 32 + lq;                                         \
    _Pragma("unroll")                                                          \
    for (int k_ = 0; k_ < 4; ++k_)                                             \
      aA[m_][k_] = *(const bf16x8*)(Ab_ + row_ * 128 +                         \
                                    (((k_ * 2 + hi) ^ (row_ & 7)) * 16));      \
  } } while (0)

#define RD_B(buf, arr) do {                                                    \
  const char* Bb_ = (buf);                                                     \
  int row_ = wn * 32 + lq;                                                     \
  _Pragma("unroll")                                                            \
  for (int k_ = 0; k_ < 4; ++k_)                                               \
    arr[k_] = *(const bf16x8*)(Bb_ + row_ * 128 +                              \
                               (((k_ * 2 + hi) ^ (row_ & 7)) * 16));           \
  } while (0)

#define DO_MFMA(mh, nh, arr, tail) do {                                        \
  __builtin_amdgcn_s_barrier();                                                \
  asm volatile("s_waitcnt lgkmcnt(0)");                                        \
  __builtin_amdgcn_s_setprio(1);                                               \
  _Pragma("unroll")                                                            \
  for (int m_ = 0; m_ < 2; ++m_)                                               \
    _Pragma("unroll")                                                          \
    for (int k_ = 0; k_ < 4; ++k_)                                             \
      acc[(mh) * 2 + m_][nh] = __builtin_amdgcn_mfma_f32_32x32x16_bf16(        \
          aA[m_][k_], arr[k_], acc[(mh) * 2 + m_][nh], 0, 0, 0);               \
  __builtin_amdgcn_s_setprio(0);                                               \
  tail;                                                                        \
  __builtin_amdgcn_s_barrier();                                                \
} while (0)

template<bool QKV, bool OUT_BF16>
__global__ __launch_bounds__(512, 2) void gemm256(const unsigned short* __restrict__ A,
                                                  const unsigned short* __restrict__ B0,
                                                  const unsigned short* __restrict__ B1,
                                                  const unsigned short* __restrict__ B2,
                                                  void* __restrict__ C0,
                                                  void* __restrict__ C1,
                                                  void* __restrict__ C2,
                                                  int M, int N, int K,
                                                  const float* __restrict__ fc,
                                                  const float* __restrict__ fs){
  __shared__ char LDS[131072];
  const int tid = threadIdx.x;
  const int l = tid & 63, w = tid >> 6;
  const int lq = l & 31, hi = l >> 5;
  const int wm = w >> 2, wn = w & 3;     // 2M x 4N wave grid

  const int cpx = gridDim.x >> 3;
  const int orig = blockIdx.x;
  const int sw = (orig & 7) * cpx + (orig >> 3);
  const int nbc = QKV ? 24 : (N >> 8);
  const int br = sw / nbc, bcg = sw % nbc;
  const int wsel = QKV ? (bcg >> 3) : 0;
  const int bc = QKV ? (bcg & 7) : bcg;
  const unsigned short* Bg = (QKV ? (wsel == 0 ? B0 : wsel == 1 ? B1 : B2) : B0)
                             + (size_t)bc * 256 * K;
  void* Cv = QKV ? (wsel == 0 ? C0 : wsel == 1 ? C1 : C2) : C0;
  const bool rope = QKV && (wsel < 2);

  f32x16 acc[4][2] = {};
  bf16x8 aA[2][4], bB0[4], bB1[4];
  const unsigned short* Ag = A + (size_t)br * 256 * K;
  const int NT = K >> 6;

  STAGE(0, Ag, 0, 0, 0); STAGE(1, Bg, 0, 0, 0);
  STAGE(0, Ag, 1, 0, 0); STAGE(1, Bg, 1, 0, 0);
  STAGE(1, Bg, 0, 1, 1); STAGE(0, Ag, 0, 1, 1);
  asm volatile("s_waitcnt vmcnt(4)" ::: "memory");
  __builtin_amdgcn_s_barrier();

  for (int t = 0; t < NT; ++t){
    const int par = t & 1, parn = par ^ 1;
    RD_A(BUF(0, 0, par));
    RD_B(BUF(1, 0, par), bB0);
    if (t + 1 < NT) STAGE(0, Ag, 1, parn, t + 1);
    DO_MFMA(0, 0, bB0, (void)0);
    RD_B(BUF(1, 1, par), bB1);
    if (t + 1 < NT) STAGE(1, Bg, 1, parn, t + 1);
    DO_MFMA(0, 1, bB1, (void)0);
    RD_A(BUF(0, 1, par));
    if (t + 2 < NT) STAGE(0, Ag, 0, par, t + 2);
    DO_MFMA(1, 0, bB0, (void)0);
    if (t + 2 < NT) STAGE(1, Bg, 0, par, t + 2);
    DO_MFMA(1, 1, bB1, asm volatile("s_waitcnt vmcnt(4)" ::: "memory"));
  }

  // epilogue: C layout (32x32): col = lane&31 (B side), row = (reg&3)+8*(reg>>2)+4*hi
#pragma unroll
  for (int i = 0; i < 4; ++i){
    int rowb = br * 256 + (i >> 1) * 128 + wm * 64 + (i & 1) * 32;
#pragma unroll
    for (int nh = 0; nh < 2; ++nh){
      int gcol = bc * 256 + nh * 128 + wn * 32 + lq;
#pragma unroll
      for (int r = 0; r < 16; ++r){
        int grow = rowb + (r & 3) + 8 * (r >> 2) + 4 * hi;
        float v = acc[i][nh][r];
        if (rope){
          int s = grow & 2047;
          int i0 = (gcol & 127) >> 1;
          float cc = fc[s * 64 + i0], sn = fs[s * 64 + i0];
          float part = __shfl_xor(v, 1, 64);
          v = (lq & 1) ? __builtin_fmaf(part, sn, v * cc)
                       : __builtin_fmaf(-part, sn, v * cc);
        }
        if (OUT_BF16){
          unsigned wb = f2bf(v);
          unsigned pn = __shfl_xor((int)wb, 1, 64);
          if (!(lq & 1))
            *(unsigned*)((unsigned short*)Cv + (size_t)grow * N + gcol) = wb | (pn << 16);
        } else {
          ((float*)Cv)[(size_t)grow * N + gcol] = v;
        }
      }
    }
  }
}

// ---------------- Flash attention (causal), swapped-QK^T, 8 waves, dbuf ----------------
// No online-max: Q pre-scaled by log2e/sqrt(d); p = exp2(s); final 1/lrow normalize.
__global__ __launch_bounds__(512, 2) void attn_fwd(const unsigned short* __restrict__ Q,
                                                   const unsigned short* __restrict__ K,
                                                   const unsigned short* __restrict__ V,
                                                   unsigned short* __restrict__ O){
  __shared__ unsigned short SMEM[2 * 64 * 128 + 2 * 128 * 64];   // 64 KB
  unsigned short* Ks = SMEM;
  unsigned short* Vt = SMEM + 16384;

  const int tid = threadIdx.x;
  const int l = tid & 63, wid = tid >> 6;
  const int lq = l & 31, hi = l >> 5;
  const int bh = blockIdx.x & 63;
  const int tsel = blockIdx.x >> 8;
  const int kidx = (blockIdx.x >> 6) & 3;
  const int qt = tsel ? kidx : 7 - kidx;          // pairs (i,i+256): (7,0),(6,1),(5,2),(4,3)
  const int b = bh >> 4, h = bh & 15;
  const int qw = qt * 256 + wid * 32;
  const float c2 = 0.12751743f;                   // (1/sqrt(128)) * log2(e)

  const unsigned short* qptr = Q + ((size_t)(b * 2048 + qw + lq)) * 2048 + (size_t)h * 128;
  bf16x8 qf[8];
#pragma unroll
  for (int ks = 0; ks < 8; ++ks){
    u16x8 qr = *(const u16x8*)(qptr + ks * 16 + hi * 8);
    union { unsigned u[4]; bf16x8 v; } qq;
#pragma unroll
    for (int e = 0; e < 4; ++e)
      qq.u[e] = cvtpk(bf2f(qr[2 * e]) * c2, bf2f(qr[2 * e + 1]) * c2);
    qf[ks] = qq.v;
  }

  f32x16 oacc[4];
#pragma unroll
  for (int i = 0; i < 4; ++i)
#pragma unroll
    for (int j = 0; j < 16; ++j) oacc[i][j] = 0.f;
  float lrow = 0.f;

  const int dblk = tid >> 5, kvp = tid & 31;
  const size_t hb = (size_t)b * 2048 * 2048 + (size_t)h * 128;
  u16x8 r0, r1;

  {
    const size_t kvb = hb;
#pragma unroll
    for (int c = 0; c < 2; ++c){
      int off = c * 8192 + tid * 16;
      int row = off >> 8, colb = off & 255;
      gload_lds16((const char*)(K + kvb + (size_t)row * 2048) + (colb ^ ((row & 15) << 4)),
                  (char*)Ks + c * 8192 + (tid >> 6) * 1024 + (tid & 63) * 16);
    }
    const unsigned short* vp = V + kvb + (size_t)(2 * kvp) * 2048 + dblk * 8;
    r0 = *(const u16x8*)vp; r1 = *(const u16x8*)(vp + 2048);
    asm volatile("s_waitcnt vmcnt(0)" ::: "memory");
#pragma unroll
    for (int j = 0; j < 8; ++j){
      int d = dblk * 8 + j;
      unsigned val = (unsigned)r0[j] | ((unsigned)r1[j] << 16);
      *(unsigned*)((char*)Vt + d * 128 + ((4 * kvp) ^ ((d & 7) << 4))) = val;
    }
  }
  __syncthreads();

  const int nkt = 4 * qt + 4;
  for (int kt = 0; kt < nkt; ++kt){
    const int cur = kt & 1, nxt = cur ^ 1;
    const bool pref = (kt + 1 < nkt);
    char* KsC = (char*)(Ks + cur * 8192);
    char* VtC = (char*)(Vt + cur * 8192);

    if (pref){
      const size_t kvb = hb + (size_t)((kt + 1) * 64) * 2048;
      char* KsN = (char*)(Ks + nxt * 8192);
#pragma unroll
      for (int c = 0; c < 2; ++c){
        int off = c * 8192 + tid * 16;
        int row = off >> 8, colb = off & 255;
        gload_lds16((const char*)(K + kvb + (size_t)row * 2048) + (colb ^ ((row & 15) << 4)),
                    KsN + c * 8192 + (tid >> 6) * 1024 + (tid & 63) * 16);
      }
      const unsigned short* vp = V + kvb + (size_t)(2 * kvp) * 2048 + dblk * 8;
      r0 = *(const u16x8*)vp; r1 = *(const u16x8*)(vp + 2048);
    }

    if (!(kt * 64 > qw + 31)){
      f32x16 sacc[2];
#pragma unroll
      for (int sub = 0; sub < 2; ++sub){
#pragma unroll
        for (int j = 0; j < 16; ++j) sacc[sub][j] = 0.f;
        const int row = sub * 32 + lq;
        const int swz = (row & 15) << 4;
#pragma unroll
        for (int ks = 0; ks < 8; ++ks){
          bf16x8 kf = *(const bf16x8*)(KsC + row * 256 + ((ks * 32 + hi * 16) ^ swz));
          sacc[sub] = __builtin_amdgcn_mfma_f32_32x32x16_bf16(kf, qf[ks], sacc[sub], 0, 0, 0);
        }
      }

      float s[32];
#pragma unroll
      for (int sub = 0; sub < 2; ++sub)
#pragma unroll
        for (int r = 0; r < 16; ++r) s[sub * 16 + r] = sacc[sub][r];

      if (kt * 64 + 63 > qw){
        const int qg = qw + lq;
#pragma unroll
        for (int sub = 0; sub < 2; ++sub)
#pragma unroll
          for (int r = 0; r < 16; ++r){
            int kvg = kt * 64 + sub * 32 + (r & 3) + 8 * (r >> 2) + 4 * hi;
            if (kvg > qg) s[sub * 16 + r] = -3.0e38f;
          }
      }

      float p[32];
#pragma unroll
      for (int i = 0; i < 32; ++i)
        p[i] = __builtin_amdgcn_exp2f(s[i]);
      float sm[32];
#pragma unroll
      for (int i = 0; i < 32; ++i) sm[i] = p[i];
#pragma unroll
      for (int st = 1; st < 32; st <<= 1)
#pragma unroll
        for (int i = 0; i < 32; i += 2 * st) sm[i] += sm[i + st];
      lrow += xsum32(sm[0]);

      unsigned wv[16];
#pragma unroll
      for (int i = 0; i < 16; ++i) wv[i] = cvtpk(p[2 * i], p[2 * i + 1]);
      swap32(wv[0], wv[2]);   swap32(wv[1], wv[3]);
      swap32(wv[4], wv[6]);   swap32(wv[5], wv[7]);
      swap32(wv[8], wv[10]);  swap32(wv[9], wv[11]);
      swap32(wv[12], wv[14]); swap32(wv[13], wv[15]);

#pragma unroll
      for (int c = 0; c < 4; ++c){
        union { unsigned u[4]; bf16x8 v; } pu;
        pu.u[0] = wv[c * 4 + 0]; pu.u[1] = wv[c * 4 + 1];
        pu.u[2] = wv[c * 4 + 2]; pu.u[3] = wv[c * 4 + 3];
#pragma unroll
        for (int db = 0; db < 4; ++db){
          const int d = db * 32 + lq;
          bf16x8 vf = *(const bf16x8*)(VtC + d * 128 + ((c * 32 + hi * 16) ^ ((d & 7) << 4)));
          oacc[db] = __builtin_amdgcn_mfma_f32_32x32x16_bf16(vf, pu.v, oacc[db], 0, 0, 0);
        }
      }
    }

    if (pref){
      asm volatile("s_waitcnt vmcnt(0)" ::: "memory");
      char* VtN = (char*)(Vt + nxt * 8192);
#pragma unroll
      for (int j = 0; j < 8; ++j){
        int d = dblk * 8 + j;
        unsigned val = (unsigned)r0[j] | ((unsigned)r1[j] << 16);
        *(unsigned*)(VtN + d * 128 + ((4 * kvp) ^ ((d & 7) << 4))) = val;
      }
    }
    __syncthreads();
  }

  float inv = 1.0f / lrow;
  char* lb = (char*)SMEM + wid * 8192;
#pragma unroll
  for (int db = 0; db < 4; ++db)
#pragma unroll
    for (int r = 0; r < 16; r += 2){
      int d = db * 32 + (r & 3) + 8 * (r >> 2) + 4 * hi;
      unsigned val = (unsigned)f2bf(oacc[db][r] * inv) |
                     ((unsigned)f2bf(oacc[db][r + 1] * inv) << 16);
      *(unsigned*)(lb + lq * 256 + ((2 * d) ^ ((lq & 7) << 4))) = val;
    }
  __syncthreads();
#pragma unroll
  for (int i = 0; i < 8; ++i){
    int rowq = i * 4 + (l >> 4);
    u16x8 vv = *(const u16x8*)(lb + rowq * 256 + (((l & 15) * 16) ^ ((rowq & 7) << 4)));
    *(u16x8*)(O + ((size_t)(b * 2048 + qw + rowq)) * 2048 + (size_t)h * 128 + (l & 15) * 8) = vv;
  }
}

// ---------------- host-side launch ----------------
extern "C" void kernel_launch(void* const* d_in, const int* in_sizes, int n_in,
                              void* d_out, int out_size, void* d_ws, size_t ws_size,
                              hipStream_t stream){
  const float* x  = (const float*)d_in[0];
  const float* wq = (const float*)d_in[1];
  const float* wk = (const float*)d_in[2];
  const float* wv = (const float*)d_in[3];
  const float* wo = (const float*)d_in[4];
  const float* fc = (const float*)d_in[5];
  const float* fs = (const float*)d_in[6];
  float* out = (float*)d_out;
  (void)in_sizes; (void)n_in; (void)out_size; (void)ws_size;

  const size_t XN = (size_t)8192 * 2048;
  const size_t WN = (size_t)2048 * 2048;

  unsigned short* xb  = (unsigned short*)d_ws;
  unsigned short* wqb = xb + XN;
  unsigned short* wkb = wqb + WN;
  unsigned short* wvb = wkb + WN;
  unsigned short* wob = wvb + WN;
  unsigned short* q   = wob + WN;
  unsigned short* k   = q + XN;
  unsigned short* v   = k + XN;
  unsigned short* att = xb;                // alias: x-bf16 dead after QKV GEMM

  cvt_f32_bf16<<<dim3((unsigned)(XN / 1024)), 256, 0, stream>>>(x, xb);
  cvt_w4<<<dim3((unsigned)(WN / 1024), 4), 256, 0, stream>>>(wq, wk, wv, wo, wqb, wkb, wvb, wob);

  // fused QKV projection (768 blocks = 32 br x 24 bc; RoPE on Q,K)
  gemm256<true, true><<<dim3(768), 512, 0, stream>>>(xb, wqb, wkb, wvb,
                                                     q, k, v, 8192, 2048, 2048, fc, fs);

  attn_fwd<<<dim3(512), 512, 0, stream>>>(q, k, v, att);

  gemm256<false, false><<<dim3(256), 512, 0, stream>>>(att, wob, wob, wob,
                                                       out, out, out, 8192, 2048, 2048,
                                                       nullptr, nullptr);
}

// Round 10
// 455.884 us; speedup vs baseline: 1.0841x; 1.0841x over previous
//
#include <hip/hip_runtime.h>

typedef __attribute__((ext_vector_type(8))) __bf16 bf16x8;
typedef __attribute__((ext_vector_type(4))) float f32x4;
typedef __attribute__((ext_vector_type(16))) float f32x16;
typedef __attribute__((ext_vector_type(8))) unsigned short u16x8;
typedef __attribute__((ext_vector_type(2))) unsigned uint2v;

__device__ __forceinline__ unsigned short f2bf(float f){
  union { float f; unsigned u; } v; v.f = f;
  unsigned r = v.u + 0x7FFFu + ((v.u >> 16) & 1u);
  return (unsigned short)(r >> 16);
}
__device__ __forceinline__ float bf2f(unsigned short u){
  union { unsigned u; float f; } v; v.u = ((unsigned)u) << 16;
  return v.f;
}

typedef const unsigned __attribute__((address_space(1)))* gas_ptr;
typedef unsigned __attribute__((address_space(3)))* las_ptr;

__device__ __forceinline__ void gload_lds16(const void* g, void* l){
  __builtin_amdgcn_global_load_lds((gas_ptr)g, (las_ptr)l, 16, 0, 0);
}

__device__ __forceinline__ unsigned cvtpk(float lo, float hi){
  unsigned r;
  asm("v_cvt_pk_bf16_f32 %0, %1, %2" : "=v"(r) : "v"(lo), "v"(hi));
  return r;
}
__device__ __forceinline__ void swap32(unsigned &a, unsigned &b){
  uint2v r = __builtin_amdgcn_permlane32_swap(a, b, false, false);
  a = r[0]; b = r[1];
}
__device__ __forceinline__ float xsum32(float v){
  union { float f; unsigned u; } a; a.f = v;
  uint2v r = __builtin_amdgcn_permlane32_swap(a.u, a.u, false, false);
  union { unsigned u; float f; } x, y; x.u = r[0]; y.u = r[1];
  return x.f + y.f;
}

// ---------------- f32 -> bf16 conversion ----------------
__global__ __launch_bounds__(256) void cvt_f32_bf16(const float* __restrict__ in,
                                                    unsigned short* __restrict__ out){
  size_t i = ((size_t)blockIdx.x * 256 + threadIdx.x) * 4;
  float4 vv = *(const float4*)(in + i);
  ushort4 o;
  o.x = f2bf(vv.x); o.y = f2bf(vv.y); o.z = f2bf(vv.z); o.w = f2bf(vv.w);
  *(ushort4*)(out + i) = o;
}
__global__ __launch_bounds__(256) void cvt_w4(const float* __restrict__ w0, const float* __restrict__ w1,
                                              const float* __restrict__ w2, const float* __restrict__ w3,
                                              unsigned short* o0, unsigned short* o1,
                                              unsigned short* o2, unsigned short* o3){
  const float* in = blockIdx.y == 0 ? w0 : blockIdx.y == 1 ? w1 : blockIdx.y == 2 ? w2 : w3;
  unsigned short* out = blockIdx.y == 0 ? o0 : blockIdx.y == 1 ? o1 : blockIdx.y == 2 ? o2 : o3;
  size_t i = ((size_t)blockIdx.x * 256 + threadIdx.x) * 4;
  float4 vv = *(const float4*)(in + i);
  ushort4 o;
  o.x = f2bf(vv.x); o.y = f2bf(vv.y); o.z = f2bf(vv.z); o.w = f2bf(vv.w);
  *(ushort4*)(out + i) = o;
}

// ============ 256x256 GEMM, 32x32x16 MFMA, 4-phase, reg-cached ============
// C[M,N] = A[M,K] * B[N,K]^T. Separate launch per projection (fusion thrashes
// L2/L3 weight streams -- R9 post-mortem). 24 ds_read_b128 / wave / K-tile;
// stage schedule and vmcnt(4) boundary as verified in R6.
#define BUF(op, half, par) (LDS + (((op) * 2 + (half)) * 2 + (par)) * 16384)

#define STAGE(op, gbase, half, par, kt) do {                                   \
  _Pragma("unroll")                                                            \
  for (int c_ = 0; c_ < 2; ++c_){                                              \
    int slot_ = c_ * 512 + w * 64 + l;                                         \
    int row_ = slot_ >> 3, colb_ = slot_ & 7;                                  \
    gload_lds16((const char*)((gbase) + (size_t)((half) * 128 + row_) * K +    \
                              (size_t)(kt) * 64 + ((colb_ ^ (row_ & 7)) * 8)), \
                BUF(op, half, par) + c_ * 8192 + w * 1024);                    \
  } } while (0)

#define RD_A(buf) do {                                                         \
  const char* Ab_ = (buf);                                                     \
  _Pragma("unroll")                                                            \
  for (int m_ = 0; m_ < 2; ++m_){                                              \
    int row_ = wm * 64 + m_ * 32 + lq;                                         \
    _Pragma("unroll")                                                          \
    for (int k_ = 0; k_ < 4; ++k_)                                             \
      aA[m_][k_] = *(const bf16x8*)(Ab_ + row_ * 128 +                         \
                                    (((k_ * 2 + hi) ^ (row_ & 7)) * 16));      \
  } } while (0)

#define RD_B(buf, arr) do {                                                    \
  const char* Bb_ = (buf);                                                     \
  int row_ = wn * 32 + lq;                                                     \
  _Pragma("unroll")                                                            \
  for (int k_ = 0; k_ < 4; ++k_)                                               \
    arr[k_] = *(const bf16x8*)(Bb_ + row_ * 128 +                              \
                               (((k_ * 2 + hi) ^ (row_ & 7)) * 16));           \
  } while (0)

#define DO_MFMA(mh, nh, arr, tail) do {                                        \
  __builtin_amdgcn_s_barrier();                                                \
  asm volatile("s_waitcnt lgkmcnt(0)");                                        \
  __builtin_amdgcn_s_setprio(1);                                               \
  _Pragma("unroll")                                                            \
  for (int m_ = 0; m_ < 2; ++m_)                                               \
    _Pragma("unroll")                                                          \
    for (int k_ = 0; k_ < 4; ++k_)                                             \
      acc[(mh) * 2 + m_][nh] = __builtin_amdgcn_mfma_f32_32x32x16_bf16(        \
          aA[m_][k_], arr[k_], acc[(mh) * 2 + m_][nh], 0, 0, 0);               \
  __builtin_amdgcn_s_setprio(0);                                               \
  tail;                                                                        \
  __builtin_amdgcn_s_barrier();                                                \
} while (0)

template<bool OUT_BF16, bool ROPE>
__global__ __launch_bounds__(512, 2) void gemm256(const unsigned short* __restrict__ A,
                                                  const unsigned short* __restrict__ B,
                                                  void* __restrict__ Cv,
                                                  int M, int N, int K,
                                                  const float* __restrict__ fc,
                                                  const float* __restrict__ fs){
  __shared__ char LDS[131072];
  const int tid = threadIdx.x;
  const int l = tid & 63, w = tid >> 6;
  const int lq = l & 31, hi = l >> 5;
  const int wm = w >> 2, wn = w & 3;     // 2M x 4N wave grid

  const int cpx = gridDim.x >> 3;
  const int orig = blockIdx.x;
  const int sw = (orig & 7) * cpx + (orig >> 3);
  const int nbc = N >> 8;
  const int br = sw / nbc, bc = sw % nbc;

  f32x16 acc[4][2] = {};
  bf16x8 aA[2][4], bB0[4], bB1[4];
  const unsigned short* Ag = A + (size_t)br * 256 * K;
  const unsigned short* Bg = B + (size_t)bc * 256 * K;
  const int NT = K >> 6;

  STAGE(0, Ag, 0, 0, 0); STAGE(1, Bg, 0, 0, 0);
  STAGE(0, Ag, 1, 0, 0); STAGE(1, Bg, 1, 0, 0);
  STAGE(1, Bg, 0, 1, 1); STAGE(0, Ag, 0, 1, 1);
  asm volatile("s_waitcnt vmcnt(4)" ::: "memory");
  __builtin_amdgcn_s_barrier();

  for (int t = 0; t < NT; ++t){
    const int par = t & 1, parn = par ^ 1;
    RD_A(BUF(0, 0, par));
    RD_B(BUF(1, 0, par), bB0);
    if (t + 1 < NT) STAGE(0, Ag, 1, parn, t + 1);
    DO_MFMA(0, 0, bB0, (void)0);
    RD_B(BUF(1, 1, par), bB1);
    if (t + 1 < NT) STAGE(1, Bg, 1, parn, t + 1);
    DO_MFMA(0, 1, bB1, (void)0);
    RD_A(BUF(0, 1, par));
    if (t + 2 < NT) STAGE(0, Ag, 0, par, t + 2);
    DO_MFMA(1, 0, bB0, (void)0);
    if (t + 2 < NT) STAGE(1, Bg, 0, par, t + 2);
    DO_MFMA(1, 1, bB1, asm volatile("s_waitcnt vmcnt(4)" ::: "memory"));
  }

  // epilogue: C layout (32x32): col = lane&31 (B side), row = (reg&3)+8*(reg>>2)+4*hi
#pragma unroll
  for (int i = 0; i < 4; ++i){
    int rowb = br * 256 + (i >> 1) * 128 + wm * 64 + (i & 1) * 32;
#pragma unroll
    for (int nh = 0; nh < 2; ++nh){
      int gcol = bc * 256 + nh * 128 + wn * 32 + lq;
#pragma unroll
      for (int r = 0; r < 16; ++r){
        int grow = rowb + (r & 3) + 8 * (r >> 2) + 4 * hi;
        float v = acc[i][nh][r];
        if (ROPE){
          int s = grow & 2047;
          int i0 = (gcol & 127) >> 1;
          float cc = fc[s * 64 + i0], sn = fs[s * 64 + i0];
          float part = __shfl_xor(v, 1, 64);
          v = (lq & 1) ? __builtin_fmaf(part, sn, v * cc)
                       : __builtin_fmaf(-part, sn, v * cc);
        }
        if (OUT_BF16){
          unsigned wb = f2bf(v);
          unsigned pn = __shfl_xor((int)wb, 1, 64);
          if (!(lq & 1))
            *(unsigned*)((unsigned short*)Cv + (size_t)grow * N + gcol) = wb | (pn << 16);
        } else {
          ((float*)Cv)[(size_t)grow * N + gcol] = v;
        }
      }
    }
  }
}

// ---------------- Flash attention (causal), swapped-QK^T, 8 waves, dbuf ----------------
// No online-max: Q pre-scaled by log2e/sqrt(d); p = exp2(s); final 1/lrow normalize.
__global__ __launch_bounds__(512, 2) void attn_fwd(const unsigned short* __restrict__ Q,
                                                   const unsigned short* __restrict__ K,
                                                   const unsigned short* __restrict__ V,
                                                   unsigned short* __restrict__ O){
  __shared__ unsigned short SMEM[2 * 64 * 128 + 2 * 128 * 64];   // 64 KB
  unsigned short* Ks = SMEM;
  unsigned short* Vt = SMEM + 16384;

  const int tid = threadIdx.x;
  const int l = tid & 63, wid = tid >> 6;
  const int lq = l & 31, hi = l >> 5;
  const int bh = blockIdx.x & 63;
  const int tsel = blockIdx.x >> 8;
  const int kidx = (blockIdx.x >> 6) & 3;
  const int qt = tsel ? kidx : 7 - kidx;          // pairs (i,i+256): (7,0),(6,1),(5,2),(4,3)
  const int b = bh >> 4, h = bh & 15;
  const int qw = qt * 256 + wid * 32;
  const float c2 = 0.12751743f;                   // (1/sqrt(128)) * log2(e)

  const unsigned short* qptr = Q + ((size_t)(b * 2048 + qw + lq)) * 2048 + (size_t)h * 128;
  bf16x8 qf[8];
#pragma unroll
  for (int ks = 0; ks < 8; ++ks){
    u16x8 qr = *(const u16x8*)(qptr + ks * 16 + hi * 8);
    union { unsigned u[4]; bf16x8 v; } qq;
#pragma unroll
    for (int e = 0; e < 4; ++e)
      qq.u[e] = cvtpk(bf2f(qr[2 * e]) * c2, bf2f(qr[2 * e + 1]) * c2);
    qf[ks] = qq.v;
  }

  f32x16 oacc[4];
#pragma unroll
  for (int i = 0; i < 4; ++i)
#pragma unroll
    for (int j = 0; j < 16; ++j) oacc[i][j] = 0.f;
  float lrow = 0.f;

  const int dblk = tid >> 5, kvp = tid & 31;
  const size_t hb = (size_t)b * 2048 * 2048 + (size_t)h * 128;
  u16x8 r0, r1;

  {
    const size_t kvb = hb;
#pragma unroll
    for (int c = 0; c < 2; ++c){
      int off = c * 8192 + tid * 16;
      int row = off >> 8, colb = off & 255;
      gload_lds16((const char*)(K + kvb + (size_t)row * 2048) + (colb ^ ((row & 15) << 4)),
                  (char*)Ks + c * 8192 + (tid >> 6) * 1024 + (tid & 63) * 16);
    }
    const unsigned short* vp = V + kvb + (size_t)(2 * kvp) * 2048 + dblk * 8;
    r0 = *(const u16x8*)vp; r1 = *(const u16x8*)(vp + 2048);
    asm volatile("s_waitcnt vmcnt(0)" ::: "memory");
#pragma unroll
    for (int j = 0; j < 8; ++j){
      int d = dblk * 8 + j;
      unsigned val = (unsigned)r0[j] | ((unsigned)r1[j] << 16);
      *(unsigned*)((char*)Vt + d * 128 + ((4 * kvp) ^ ((d & 7) << 4))) = val;
    }
  }
  __syncthreads();

  const int nkt = 4 * qt + 4;
  for (int kt = 0; kt < nkt; ++kt){
    const int cur = kt & 1, nxt = cur ^ 1;
    const bool pref = (kt + 1 < nkt);
    char* KsC = (char*)(Ks + cur * 8192);
    char* VtC = (char*)(Vt + cur * 8192);

    if (pref){
      const size_t kvb = hb + (size_t)((kt + 1) * 64) * 2048;
      char* KsN = (char*)(Ks + nxt * 8192);
#pragma unroll
      for (int c = 0; c < 2; ++c){
        int off = c * 8192 + tid * 16;
        int row = off >> 8, colb = off & 255;
        gload_lds16((const char*)(K + kvb + (size_t)row * 2048) + (colb ^ ((row & 15) << 4)),
                    KsN + c * 8192 + (tid >> 6) * 1024 + (tid & 63) * 16);
      }
      const unsigned short* vp = V + kvb + (size_t)(2 * kvp) * 2048 + dblk * 8;
      r0 = *(const u16x8*)vp; r1 = *(const u16x8*)(vp + 2048);
    }

    if (!(kt * 64 > qw + 31)){
      f32x16 sacc[2];
#pragma unroll
      for (int sub = 0; sub < 2; ++sub){
#pragma unroll
        for (int j = 0; j < 16; ++j) sacc[sub][j] = 0.f;
        const int row = sub * 32 + lq;
        const int swz = (row & 15) << 4;
#pragma unroll
        for (int ks = 0; ks < 8; ++ks){
          bf16x8 kf = *(const bf16x8*)(KsC + row * 256 + ((ks * 32 + hi * 16) ^ swz));
          sacc[sub] = __builtin_amdgcn_mfma_f32_32x32x16_bf16(kf, qf[ks], sacc[sub], 0, 0, 0);
        }
      }

      float s[32];
#pragma unroll
      for (int sub = 0; sub < 2; ++sub)
#pragma unroll
        for (int r = 0; r < 16; ++r) s[sub * 16 + r] = sacc[sub][r];

      if (kt * 64 + 63 > qw){
        const int qg = qw + lq;
#pragma unroll
        for (int sub = 0; sub < 2; ++sub)
#pragma unroll
          for (int r = 0; r < 16; ++r){
            int kvg = kt * 64 + sub * 32 + (r & 3) + 8 * (r >> 2) + 4 * hi;
            if (kvg > qg) s[sub * 16 + r] = -3.0e38f;
          }
      }

      float p[32];
#pragma unroll
      for (int i = 0; i < 32; ++i)
        p[i] = __builtin_amdgcn_exp2f(s[i]);
      float sm[32];
#pragma unroll
      for (int i = 0; i < 32; ++i) sm[i] = p[i];
#pragma unroll
      for (int st = 1; st < 32; st <<= 1)
#pragma unroll
        for (int i = 0; i < 32; i += 2 * st) sm[i] += sm[i + st];
      lrow += xsum32(sm[0]);

      unsigned wv[16];
#pragma unroll
      for (int i = 0; i < 16; ++i) wv[i] = cvtpk(p[2 * i], p[2 * i + 1]);
      swap32(wv[0], wv[2]);   swap32(wv[1], wv[3]);
      swap32(wv[4], wv[6]);   swap32(wv[5], wv[7]);
      swap32(wv[8], wv[10]);  swap32(wv[9], wv[11]);
      swap32(wv[12], wv[14]); swap32(wv[13], wv[15]);

#pragma unroll
      for (int c = 0; c < 4; ++c){
        union { unsigned u[4]; bf16x8 v; } pu;
        pu.u[0] = wv[c * 4 + 0]; pu.u[1] = wv[c * 4 + 1];
        pu.u[2] = wv[c * 4 + 2]; pu.u[3] = wv[c * 4 + 3];
#pragma unroll
        for (int db = 0; db < 4; ++db){
          const int d = db * 32 + lq;
          bf16x8 vf = *(const bf16x8*)(VtC + d * 128 + ((c * 32 + hi * 16) ^ ((d & 7) << 4)));
          oacc[db] = __builtin_amdgcn_mfma_f32_32x32x16_bf16(vf, pu.v, oacc[db], 0, 0, 0);
        }
      }
    }

    if (pref){
      asm volatile("s_waitcnt vmcnt(0)" ::: "memory");
      char* VtN = (char*)(Vt + nxt * 8192);
#pragma unroll
      for (int j = 0; j < 8; ++j){
        int d = dblk * 8 + j;
        unsigned val = (unsigned)r0[j] | ((unsigned)r1[j] << 16);
        *(unsigned*)(VtN + d * 128 + ((4 * kvp) ^ ((d & 7) << 4))) = val;
      }
    }
    __syncthreads();
  }

  float inv = 1.0f / lrow;
  char* lb = (char*)SMEM + wid * 8192;
#pragma unroll
  for (int db = 0; db < 4; ++db)
#pragma unroll
    for (int r = 0; r < 16; r += 2){
      int d = db * 32 + (r & 3) + 8 * (r >> 2) + 4 * hi;
      unsigned val = (unsigned)f2bf(oacc[db][r] * inv) |
                     ((unsigned)f2bf(oacc[db][r + 1] * inv) << 16);
      *(unsigned*)(lb + lq * 256 + ((2 * d) ^ ((lq & 7) << 4))) = val;
    }
  __syncthreads();
#pragma unroll
  for (int i = 0; i < 8; ++i){
    int rowq = i * 4 + (l >> 4);
    u16x8 vv = *(const u16x8*)(lb + rowq * 256 + (((l & 15) * 16) ^ ((rowq & 7) << 4)));
    *(u16x8*)(O + ((size_t)(b * 2048 + qw + rowq)) * 2048 + (size_t)h * 128 + (l & 15) * 8) = vv;
  }
}

// ---------------- host-side launch ----------------
extern "C" void kernel_launch(void* const* d_in, const int* in_sizes, int n_in,
                              void* d_out, int out_size, void* d_ws, size_t ws_size,
                              hipStream_t stream){
  const float* x  = (const float*)d_in[0];
  const float* wq = (const float*)d_in[1];
  const float* wk = (const float*)d_in[2];
  const float* wv = (const float*)d_in[3];
  const float* wo = (const float*)d_in[4];
  const float* fc = (const float*)d_in[5];
  const float* fs = (const float*)d_in[6];
  float* out = (float*)d_out;
  (void)in_sizes; (void)n_in; (void)out_size; (void)ws_size;

  const size_t XN = (size_t)8192 * 2048;
  const size_t WN = (size_t)2048 * 2048;

  unsigned short* xb  = (unsigned short*)d_ws;
  unsigned short* wqb = xb + XN;
  unsigned short* wkb = wqb + WN;
  unsigned short* wvb = wkb + WN;
  unsigned short* wob = wvb + WN;
  unsigned short* q   = wob + WN;
  unsigned short* k   = q + XN;
  unsigned short* v   = k + XN;
  unsigned short* att = xb;                // alias: x-bf16 dead after QKV GEMMs

  cvt_f32_bf16<<<dim3((unsigned)(XN / 1024)), 256, 0, stream>>>(x, xb);
  cvt_w4<<<dim3((unsigned)(WN / 1024), 4), 256, 0, stream>>>(wq, wk, wv, wo, wqb, wkb, wvb, wob);

  gemm256<true, true ><<<dim3(256), 512, 0, stream>>>(xb, wqb, q, 8192, 2048, 2048, fc, fs);
  gemm256<true, true ><<<dim3(256), 512, 0, stream>>>(xb, wkb, k, 8192, 2048, 2048, fc, fs);
  gemm256<true, false><<<dim3(256), 512, 0, stream>>>(xb, wvb, v, 8192, 2048, 2048, nullptr, nullptr);

  attn_fwd<<<dim3(512), 512, 0, stream>>>(q, k, v, att);

  gemm256<false, false><<<dim3(256), 512, 0, stream>>>(att, wob, out, 8192, 2048, 2048,
                                                       nullptr, nullptr);
}

// Round 11
// 420.311 us; speedup vs baseline: 1.1758x; 1.0846x over previous
//
#include <hip/hip_runtime.h>

typedef __attribute__((ext_vector_type(8))) __bf16 bf16x8;
typedef __attribute__((ext_vector_type(4))) float f32x4;
typedef __attribute__((ext_vector_type(16))) float f32x16;
typedef __attribute__((ext_vector_type(8))) unsigned short u16x8;
typedef __attribute__((ext_vector_type(2))) unsigned uint2v;

__device__ __forceinline__ unsigned short f2bf(float f){
  union { float f; unsigned u; } v; v.f = f;
  unsigned r = v.u + 0x7FFFu + ((v.u >> 16) & 1u);
  return (unsigned short)(r >> 16);
}
__device__ __forceinline__ float bf2f(unsigned short u){
  union { unsigned u; float f; } v; v.u = ((unsigned)u) << 16;
  return v.f;
}

typedef const unsigned __attribute__((address_space(1)))* gas_ptr;
typedef unsigned __attribute__((address_space(3)))* las_ptr;

__device__ __forceinline__ void gload_lds16(const void* g, void* l){
  __builtin_amdgcn_global_load_lds((gas_ptr)g, (las_ptr)l, 16, 0, 0);
}

__device__ __forceinline__ unsigned cvtpk(float lo, float hi){
  unsigned r;
  asm("v_cvt_pk_bf16_f32 %0, %1, %2" : "=v"(r) : "v"(lo), "v"(hi));
  return r;
}
__device__ __forceinline__ void swap32(unsigned &a, unsigned &b){
  uint2v r = __builtin_amdgcn_permlane32_swap(a, b, false, false);
  a = r[0]; b = r[1];
}
__device__ __forceinline__ float xsum32(float v){
  union { float f; unsigned u; } a; a.f = v;
  uint2v r = __builtin_amdgcn_permlane32_swap(a.u, a.u, false, false);
  union { unsigned u; float f; } x, y; x.u = r[0]; y.u = r[1];
  return x.f + y.f;
}

// ---------------- f32 -> bf16 conversion: x + 4 weights, one dispatch ----------------
__global__ __launch_bounds__(256) void cvt_all(const float* __restrict__ x,
                                               const float* __restrict__ w0, const float* __restrict__ w1,
                                               const float* __restrict__ w2, const float* __restrict__ w3,
                                               unsigned short* __restrict__ xb,
                                               unsigned short* o0, unsigned short* o1,
                                               unsigned short* o2, unsigned short* o3){
  int bid = blockIdx.x;
  const float* in; unsigned short* out; size_t base;
  if (bid < 16384){ in = x; out = xb; base = (size_t)bid * 1024; }
  else {
    int r = bid - 16384, sel = r >> 12;
    in  = sel == 0 ? w0 : sel == 1 ? w1 : sel == 2 ? w2 : w3;
    out = sel == 0 ? o0 : sel == 1 ? o1 : sel == 2 ? o2 : o3;
    base = (size_t)(r & 4095) * 1024;
  }
  size_t i = base + (size_t)threadIdx.x * 4;
  float4 vv = *(const float4*)(in + i);
  ushort4 o;
  o.x = f2bf(vv.x); o.y = f2bf(vv.y); o.z = f2bf(vv.z); o.w = f2bf(vv.w);
  *(ushort4*)(out + i) = o;
}

// ============ 256x256 GEMM, 16x16x32 MFMA, 4-phase, reg-cached (R6/R8) ============
// C[M,N] = A[M,K] * B[N,K]^T. 24 ds_read_b128 / wave / K-tile; stage schedule
// p1:A1@parn(t+1) p2:B1@parn(t+1) p3:A0@par(t+2) p4:B0@par(t+2); boundary
// vmcnt(4) folded into p4 (t+1 halves landed, t+2 halves in flight).
#define BUF(op, half, par) (LDS + (((op) * 2 + (half)) * 2 + (par)) * 16384)

#define STAGE(op, gbase, half, par, kt) do {                                   \
  _Pragma("unroll")                                                            \
  for (int c_ = 0; c_ < 2; ++c_){                                              \
    int slot_ = c_ * 512 + w * 64 + l;                                         \
    int row_ = slot_ >> 3, colb_ = slot_ & 7;                                  \
    gload_lds16((const char*)((gbase) + (size_t)((half) * 128 + row_) * K +    \
                              (size_t)(kt) * 64 + ((colb_ ^ (row_ & 7)) * 8)), \
                BUF(op, half, par) + c_ * 8192 + w * 1024);                    \
  } } while (0)

#define RD_A(buf) do {                                                         \
  const char* Ab_ = (buf);                                                     \
  _Pragma("unroll")                                                            \
  for (int i_ = 0; i_ < 4; ++i_){                                              \
    int row_ = wm * 64 + i_ * 16 + lq;                                         \
    _Pragma("unroll")                                                          \
    for (int ks_ = 0; ks_ < 2; ++ks_)                                          \
      aA[i_][ks_] = *(const bf16x8*)(Ab_ + row_ * 128 +                        \
                                     (((ks_ * 4 + lg) ^ (row_ & 7)) * 16));    \
  } } while (0)

#define RD_B(buf, arr) do {                                                    \
  const char* Bb_ = (buf);                                                     \
  _Pragma("unroll")                                                            \
  for (int j_ = 0; j_ < 2; ++j_){                                              \
    int row_ = wn * 32 + j_ * 16 + lq;                                         \
    _Pragma("unroll")                                                          \
    for (int ks_ = 0; ks_ < 2; ++ks_)                                          \
      arr[j_][ks_] = *(const bf16x8*)(Bb_ + row_ * 128 +                       \
                                      (((ks_ * 4 + lg) ^ (row_ & 7)) * 16));   \
  } } while (0)

// ks OUTER: consecutive MFMAs hit 8 distinct accumulators (dep distance 8)
#define DO_MFMA(mh, nh, arr, tail) do {                                        \
  __builtin_amdgcn_s_barrier();                                                \
  asm volatile("s_waitcnt lgkmcnt(0)");                                        \
  __builtin_amdgcn_s_setprio(1);                                               \
  _Pragma("unroll")                                                            \
  for (int ks_ = 0; ks_ < 2; ++ks_)                                            \
    _Pragma("unroll")                                                          \
    for (int i_ = 0; i_ < 4; ++i_)                                             \
      _Pragma("unroll")                                                        \
      for (int j_ = 0; j_ < 2; ++j_)                                           \
        acc[(mh) * 4 + i_][(nh) * 2 + j_] = __builtin_amdgcn_mfma_f32_16x16x32_bf16( \
            aA[i_][ks_], arr[j_][ks_], acc[(mh) * 4 + i_][(nh) * 2 + j_], 0, 0, 0); \
  __builtin_amdgcn_s_setprio(0);                                               \
  tail;                                                                        \
  __builtin_amdgcn_s_barrier();                                                \
} while (0)

template<bool OUT_BF16, bool ROPE>
__global__ __launch_bounds__(512, 2) void gemm256(const unsigned short* __restrict__ A,
                                                  const unsigned short* __restrict__ B,
                                                  void* __restrict__ Cv,
                                                  int M, int N, int K,
                                                  const float* __restrict__ fc,
                                                  const float* __restrict__ fs){
  __shared__ char LDS[131072];
  const int tid = threadIdx.x;
  const int l = tid & 63, w = tid >> 6;
  const int lq = l & 15, lg = l >> 4;
  const int wm = w >> 2, wn = w & 3;

  const int cpx = gridDim.x >> 3;
  const int orig = blockIdx.x;
  const int sw = (orig & 7) * cpx + (orig >> 3);
  const int nbc = N >> 8;
  const int br = sw / nbc, bc = sw % nbc;

  f32x4 acc[8][4] = {};
  bf16x8 aA[4][2], bB0[2][2], bB1[2][2];
  const unsigned short* Ag = A + (size_t)br * 256 * K;
  const unsigned short* Bg = B + (size_t)bc * 256 * K;
  const int NT = K >> 6;

  STAGE(0, Ag, 0, 0, 0); STAGE(1, Bg, 0, 0, 0);
  STAGE(0, Ag, 1, 0, 0); STAGE(1, Bg, 1, 0, 0);
  STAGE(1, Bg, 0, 1, 1); STAGE(0, Ag, 0, 1, 1);
  asm volatile("s_waitcnt vmcnt(4)" ::: "memory");
  __builtin_amdgcn_s_barrier();

  for (int t = 0; t < NT; ++t){
    const int par = t & 1, parn = par ^ 1;
    RD_A(BUF(0, 0, par));
    RD_B(BUF(1, 0, par), bB0);
    if (t + 1 < NT) STAGE(0, Ag, 1, parn, t + 1);
    DO_MFMA(0, 0, bB0, (void)0);
    RD_B(BUF(1, 1, par), bB1);
    if (t + 1 < NT) STAGE(1, Bg, 1, parn, t + 1);
    DO_MFMA(0, 1, bB1, (void)0);
    RD_A(BUF(0, 1, par));
    if (t + 2 < NT) STAGE(0, Ag, 0, par, t + 2);
    DO_MFMA(1, 0, bB0, (void)0);
    if (t + 2 < NT) STAGE(1, Bg, 0, par, t + 2);
    DO_MFMA(1, 1, bB1, asm volatile("s_waitcnt vmcnt(4)" ::: "memory"));
  }

  // epilogue: row = lg*4+r (A side), col = lq (B side); paired lane stores
#pragma unroll
  for (int i = 0; i < 8; ++i){
    int grow = br * 256 + (i >> 2) * 128 + wm * 64 + (i & 3) * 16 + lg * 4;
#pragma unroll
    for (int j = 0; j < 4; ++j){
      int gcol = bc * 256 + (j >> 1) * 128 + wn * 32 + (j & 1) * 16 + lq;
#pragma unroll
      for (int r = 0; r < 4; ++r){
        float v = acc[i][j][r];
        if (ROPE){
          int s = (grow + r) & 2047;
          int i0 = (gcol & 127) >> 1;
          float cc = fc[s * 64 + i0], sn = fs[s * 64 + i0];
          float part = __shfl_xor(v, 1, 64);
          v = (lq & 1) ? __builtin_fmaf(part, sn, v * cc)
                       : __builtin_fmaf(-part, sn, v * cc);
        }
        if (OUT_BF16){
          unsigned wb = f2bf(v);
          unsigned pn = __shfl_xor((int)wb, 1, 64);
          if (!(lq & 1))
            *(unsigned*)((unsigned short*)Cv + (size_t)(grow + r) * N + gcol) = wb | (pn << 16);
        } else {
          float part = __shfl_xor(v, 1, 64);
          if (!(lq & 1))
            *(float2*)((float*)Cv + (size_t)(grow + r) * N + gcol) = make_float2(v, part);
        }
      }
    }
  }
}

// ---------------- Flash attention (causal), swapped-QK^T, 8 waves, dbuf ----------------
// No online-max: Q pre-scaled by log2e/sqrt(d); p = exp2(s); final 1/lrow normalize.
__global__ __launch_bounds__(512, 2) void attn_fwd(const unsigned short* __restrict__ Q,
                                                   const unsigned short* __restrict__ K,
                                                   const unsigned short* __restrict__ V,
                                                   unsigned short* __restrict__ O){
  __shared__ unsigned short SMEM[2 * 64 * 128 + 2 * 128 * 64];   // 64 KB
  unsigned short* Ks = SMEM;
  unsigned short* Vt = SMEM + 16384;

  const int tid = threadIdx.x;
  const int l = tid & 63, wid = tid >> 6;
  const int lq = l & 31, hi = l >> 5;
  const int bh = blockIdx.x & 63;
  const int tsel = blockIdx.x >> 8;
  const int kidx = (blockIdx.x >> 6) & 3;
  const int qt = tsel ? kidx : 7 - kidx;          // pairs (i,i+256): (7,0),(6,1),(5,2),(4,3)
  const int b = bh >> 4, h = bh & 15;
  const int qw = qt * 256 + wid * 32;
  const float c2 = 0.12751743f;                   // (1/sqrt(128)) * log2(e)

  const unsigned short* qptr = Q + ((size_t)(b * 2048 + qw + lq)) * 2048 + (size_t)h * 128;
  bf16x8 qf[8];
#pragma unroll
  for (int ks = 0; ks < 8; ++ks){
    u16x8 qr = *(const u16x8*)(qptr + ks * 16 + hi * 8);
    union { unsigned u[4]; bf16x8 v; } qq;
#pragma unroll
    for (int e = 0; e < 4; ++e)
      qq.u[e] = cvtpk(bf2f(qr[2 * e]) * c2, bf2f(qr[2 * e + 1]) * c2);
    qf[ks] = qq.v;
  }

  f32x16 oacc[4];
#pragma unroll
  for (int i = 0; i < 4; ++i)
#pragma unroll
    for (int j = 0; j < 16; ++j) oacc[i][j] = 0.f;
  float lrow = 0.f;

  const int dblk = tid >> 5, kvp = tid & 31;
  const size_t hb = (size_t)b * 2048 * 2048 + (size_t)h * 128;
  u16x8 r0, r1;

  {
    const size_t kvb = hb;
#pragma unroll
    for (int c = 0; c < 2; ++c){
      int off = c * 8192 + tid * 16;
      int row = off >> 8, colb = off & 255;
      gload_lds16((const char*)(K + kvb + (size_t)row * 2048) + (colb ^ ((row & 15) << 4)),
                  (char*)Ks + c * 8192 + (tid >> 6) * 1024 + (tid & 63) * 16);
    }
    const unsigned short* vp = V + kvb + (size_t)(2 * kvp) * 2048 + dblk * 8;
    r0 = *(const u16x8*)vp; r1 = *(const u16x8*)(vp + 2048);
    asm volatile("s_waitcnt vmcnt(0)" ::: "memory");
#pragma unroll
    for (int j = 0; j < 8; ++j){
      int d = dblk * 8 + j;
      unsigned val = (unsigned)r0[j] | ((unsigned)r1[j] << 16);
      *(unsigned*)((char*)Vt + d * 128 + ((4 * kvp) ^ ((d & 7) << 4))) = val;
    }
  }
  __syncthreads();

  const int nkt = 4 * qt + 4;
  for (int kt = 0; kt < nkt; ++kt){
    const int cur = kt & 1, nxt = cur ^ 1;
    const bool pref = (kt + 1 < nkt);
    char* KsC = (char*)(Ks + cur * 8192);
    char* VtC = (char*)(Vt + cur * 8192);

    if (pref){
      const size_t kvb = hb + (size_t)((kt + 1) * 64) * 2048;
      char* KsN = (char*)(Ks + nxt * 8192);
#pragma unroll
      for (int c = 0; c < 2; ++c){
        int off = c * 8192 + tid * 16;
        int row = off >> 8, colb = off & 255;
        gload_lds16((const char*)(K + kvb + (size_t)row * 2048) + (colb ^ ((row & 15) << 4)),
                    KsN + c * 8192 + (tid >> 6) * 1024 + (tid & 63) * 16);
      }
      const unsigned short* vp = V + kvb + (size_t)(2 * kvp) * 2048 + dblk * 8;
      r0 = *(const u16x8*)vp; r1 = *(const u16x8*)(vp + 2048);
    }

    if (!(kt * 64 > qw + 31)){
      f32x16 sacc[2];
#pragma unroll
      for (int sub = 0; sub < 2; ++sub){
#pragma unroll
        for (int j = 0; j < 16; ++j) sacc[sub][j] = 0.f;
        const int row = sub * 32 + lq;
        const int swz = (row & 15) << 4;
#pragma unroll
        for (int ks = 0; ks < 8; ++ks){
          bf16x8 kf = *(const bf16x8*)(KsC + row * 256 + ((ks * 32 + hi * 16) ^ swz));
          sacc[sub] = __builtin_amdgcn_mfma_f32_32x32x16_bf16(kf, qf[ks], sacc[sub], 0, 0, 0);
        }
      }

      float s[32];
#pragma unroll
      for (int sub = 0; sub < 2; ++sub)
#pragma unroll
        for (int r = 0; r < 16; ++r) s[sub * 16 + r] = sacc[sub][r];

      if (kt * 64 + 63 > qw){
        const int qg = qw + lq;
#pragma unroll
        for (int sub = 0; sub < 2; ++sub)
#pragma unroll
          for (int r = 0; r < 16; ++r){
            int kvg = kt * 64 + sub * 32 + (r & 3) + 8 * (r >> 2) + 4 * hi;
            if (kvg > qg) s[sub * 16 + r] = -3.0e38f;
          }
      }

      float p[32];
#pragma unroll
      for (int i = 0; i < 32; ++i)
        p[i] = __builtin_amdgcn_exp2f(s[i]);
      float sm[32];
#pragma unroll
      for (int i = 0; i < 32; ++i) sm[i] = p[i];
#pragma unroll
      for (int st = 1; st < 32; st <<= 1)
#pragma unroll
        for (int i = 0; i < 32; i += 2 * st) sm[i] += sm[i + st];
      lrow += xsum32(sm[0]);

      unsigned wv[16];
#pragma unroll
      for (int i = 0; i < 16; ++i) wv[i] = cvtpk(p[2 * i], p[2 * i + 1]);
      swap32(wv[0], wv[2]);   swap32(wv[1], wv[3]);
      swap32(wv[4], wv[6]);   swap32(wv[5], wv[7]);
      swap32(wv[8], wv[10]);  swap32(wv[9], wv[11]);
      swap32(wv[12], wv[14]); swap32(wv[13], wv[15]);

#pragma unroll
      for (int c = 0; c < 4; ++c){
        union { unsigned u[4]; bf16x8 v; } pu;
        pu.u[0] = wv[c * 4 + 0]; pu.u[1] = wv[c * 4 + 1];
        pu.u[2] = wv[c * 4 + 2]; pu.u[3] = wv[c * 4 + 3];
#pragma unroll
        for (int db = 0; db < 4; ++db){
          const int d = db * 32 + lq;
          bf16x8 vf = *(const bf16x8*)(VtC + d * 128 + ((c * 32 + hi * 16) ^ ((d & 7) << 4)));
          oacc[db] = __builtin_amdgcn_mfma_f32_32x32x16_bf16(vf, pu.v, oacc[db], 0, 0, 0);
        }
      }
    }

    if (pref){
      asm volatile("s_waitcnt vmcnt(0)" ::: "memory");
      char* VtN = (char*)(Vt + nxt * 8192);
#pragma unroll
      for (int j = 0; j < 8; ++j){
        int d = dblk * 8 + j;
        unsigned val = (unsigned)r0[j] | ((unsigned)r1[j] << 16);
        *(unsigned*)(VtN + d * 128 + ((4 * kvp) ^ ((d & 7) << 4))) = val;
      }
    }
    __syncthreads();
  }

  float inv = 1.0f / lrow;
  char* lb = (char*)SMEM + wid * 8192;
#pragma unroll
  for (int db = 0; db < 4; ++db)
#pragma unroll
    for (int r = 0; r < 16; r += 2){
      int d = db * 32 + (r & 3) + 8 * (r >> 2) + 4 * hi;
      unsigned val = (unsigned)f2bf(oacc[db][r] * inv) |
                     ((unsigned)f2bf(oacc[db][r + 1] * inv) << 16);
      *(unsigned*)(lb + lq * 256 + ((2 * d) ^ ((lq & 7) << 4))) = val;
    }
  __syncthreads();
#pragma unroll
  for (int i = 0; i < 8; ++i){
    int rowq = i * 4 + (l >> 4);
    u16x8 vv = *(const u16x8*)(lb + rowq * 256 + (((l & 15) * 16) ^ ((rowq & 7) << 4)));
    *(u16x8*)(O + ((size_t)(b * 2048 + qw + rowq)) * 2048 + (size_t)h * 128 + (l & 15) * 8) = vv;
  }
}

// ---------------- host-side launch ----------------
extern "C" void kernel_launch(void* const* d_in, const int* in_sizes, int n_in,
                              void* d_out, int out_size, void* d_ws, size_t ws_size,
                              hipStream_t stream){
  const float* x  = (const float*)d_in[0];
  const float* wq = (const float*)d_in[1];
  const float* wk = (const float*)d_in[2];
  const float* wv = (const float*)d_in[3];
  const float* wo = (const float*)d_in[4];
  const float* fc = (const float*)d_in[5];
  const float* fs = (const float*)d_in[6];
  float* out = (float*)d_out;
  (void)in_sizes; (void)n_in; (void)out_size; (void)ws_size;

  const size_t XN = (size_t)8192 * 2048;
  const size_t WN = (size_t)2048 * 2048;

  unsigned short* xb  = (unsigned short*)d_ws;
  unsigned short* wqb = xb + XN;
  unsigned short* wkb = wqb + WN;
  unsigned short* wvb = wkb + WN;
  unsigned short* wob = wvb + WN;
  unsigned short* q   = wob + WN;
  unsigned short* k   = q + XN;
  unsigned short* v   = k + XN;
  unsigned short* att = xb;                // alias: x-bf16 dead after QKV GEMMs

  cvt_all<<<dim3(32768), 256, 0, stream>>>(x, wq, wk, wv, wo, xb, wqb, wkb, wvb, wob);

  gemm256<true, true ><<<dim3(256), 512, 0, stream>>>(xb, wqb, q, 8192, 2048, 2048, fc, fs);
  gemm256<true, true ><<<dim3(256), 512, 0, stream>>>(xb, wkb, k, 8192, 2048, 2048, fc, fs);
  gemm256<true, false><<<dim3(256), 512, 0, stream>>>(xb, wvb, v, 8192, 2048, 2048, nullptr, nullptr);

  attn_fwd<<<dim3(512), 512, 0, stream>>>(q, k, v, att);

  gemm256<false, false><<<dim3(256), 512, 0, stream>>>(att, wob, out, 8192, 2048, 2048,
                                                       nullptr, nullptr);
}

// Round 13
// 382.443 us; speedup vs baseline: 1.2922x; 1.0990x over previous
//
#include <hip/hip_runtime.h>

typedef __attribute__((ext_vector_type(8))) __bf16 bf16x8;
typedef __attribute__((ext_vector_type(4))) float f32x4;
typedef __attribute__((ext_vector_type(16))) float f32x16;
typedef __attribute__((ext_vector_type(8))) unsigned short u16x8;
typedef __attribute__((ext_vector_type(2))) unsigned uint2v;

__device__ __forceinline__ unsigned short f2bf(float f){
  union { float f; unsigned u; } v; v.f = f;
  unsigned r = v.u + 0x7FFFu + ((v.u >> 16) & 1u);
  return (unsigned short)(r >> 16);
}
__device__ __forceinline__ float bf2f(unsigned short u){
  union { unsigned u; float f; } v; v.u = ((unsigned)u) << 16;
  return v.f;
}

typedef const unsigned __attribute__((address_space(1)))* gas_ptr;
typedef unsigned __attribute__((address_space(3)))* las_ptr;

__device__ __forceinline__ void gload_lds16(const void* g, void* l){
  __builtin_amdgcn_global_load_lds((gas_ptr)g, (las_ptr)l, 16, 0, 0);
}

__device__ __forceinline__ unsigned cvtpk(float lo, float hi){
  unsigned r;
  asm("v_cvt_pk_bf16_f32 %0, %1, %2" : "=v"(r) : "v"(lo), "v"(hi));
  return r;
}
__device__ __forceinline__ void swap32(unsigned &a, unsigned &b){
  uint2v r = __builtin_amdgcn_permlane32_swap(a, b, false, false);
  a = r[0]; b = r[1];
}
__device__ __forceinline__ float xsum32(float v){
  union { float f; unsigned u; } a; a.f = v;
  uint2v r = __builtin_amdgcn_permlane32_swap(a.u, a.u, false, false);
  union { unsigned u; float f; } x, y; x.u = r[0]; y.u = r[1];
  return x.f + y.f;
}

// Vt swizzle: row = d (128 B of 64 kv x bf16). Chunk XOR uses (d&7)^((d>>3)&3)
// -> row-closed (<=112), bijective, and the PV lane quad {d,d+8,d+16,d+24}
// lands on 4 distinct chunks (was 4-way bank conflict with (d&7) alone).
__device__ __forceinline__ int vswz(int d){
  return ((d & 7) ^ ((d >> 3) & 3)) << 4;
}

// ---------------- f32 -> bf16 conversion: x + 4 weights, one dispatch ----------------
__global__ __launch_bounds__(256) void cvt_all(const float* __restrict__ x,
                                               const float* __restrict__ w0, const float* __restrict__ w1,
                                               const float* __restrict__ w2, const float* __restrict__ w3,
                                               unsigned short* __restrict__ xb,
                                               unsigned short* o0, unsigned short* o1,
                                               unsigned short* o2, unsigned short* o3){
  int bid = blockIdx.x;
  const float* in; unsigned short* out; size_t base;
  if (bid < 16384){ in = x; out = xb; base = (size_t)bid * 1024; }
  else {
    int r = bid - 16384, sel = r >> 12;
    in  = sel == 0 ? w0 : sel == 1 ? w1 : sel == 2 ? w2 : w3;
    out = sel == 0 ? o0 : sel == 1 ? o1 : sel == 2 ? o2 : o3;
    base = (size_t)(r & 4095) * 1024;
  }
  size_t i = base + (size_t)threadIdx.x * 4;
  float4 vv = *(const float4*)(in + i);
  ushort4 o;
  o.x = f2bf(vv.x); o.y = f2bf(vv.y); o.z = f2bf(vv.z); o.w = f2bf(vv.w);
  *(ushort4*)(out + i) = o;
}

// ============ 256x256 GEMM, 16x16x32 MFMA, 4-phase, reg-cached (R8-exact) ============
#define BUF(op, half, par) (LDS + (((op) * 2 + (half)) * 2 + (par)) * 16384)

#define STAGE(op, gbase, half, par, kt) do {                                   \
  _Pragma("unroll")                                                            \
  for (int c_ = 0; c_ < 2; ++c_){                                              \
    int slot_ = c_ * 512 + w * 64 + l;                                         \
    int row_ = slot_ >> 3, colb_ = slot_ & 7;                                  \
    gload_lds16((const char*)((gbase) + (size_t)((half) * 128 + row_) * K +    \
                              (size_t)(kt) * 64 + ((colb_ ^ (row_ & 7)) * 8)), \
                BUF(op, half, par) + c_ * 8192 + w * 1024);                    \
  } } while (0)

#define RD_A(buf) do {                                                         \
  const char* Ab_ = (buf);                                                     \
  _Pragma("unroll")                                                            \
  for (int i_ = 0; i_ < 4; ++i_){                                              \
    int row_ = wm * 64 + i_ * 16 + lq;                                         \
    _Pragma("unroll")                                                          \
    for (int ks_ = 0; ks_ < 2; ++ks_)                                          \
      aA[i_][ks_] = *(const bf16x8*)(Ab_ + row_ * 128 +                        \
                                     (((ks_ * 4 + lg) ^ (row_ & 7)) * 16));    \
  } } while (0)

#define RD_B(buf, arr) do {                                                    \
  const char* Bb_ = (buf);                                                     \
  _Pragma("unroll")                                                            \
  for (int j_ = 0; j_ < 2; ++j_){                                              \
    int row_ = wn * 32 + j_ * 16 + lq;                                         \
    _Pragma("unroll")                                                          \
    for (int ks_ = 0; ks_ < 2; ++ks_)                                          \
      arr[j_][ks_] = *(const bf16x8*)(Bb_ + row_ * 128 +                       \
                                      (((ks_ * 4 + lg) ^ (row_ & 7)) * 16));   \
  } } while (0)

#define DO_MFMA(mh, nh, arr, tail) do {                                        \
  __builtin_amdgcn_s_barrier();                                                \
  asm volatile("s_waitcnt lgkmcnt(0)");                                        \
  __builtin_amdgcn_s_setprio(1);                                               \
  _Pragma("unroll")                                                            \
  for (int i_ = 0; i_ < 4; ++i_)                                               \
    _Pragma("unroll")                                                          \
    for (int j_ = 0; j_ < 2; ++j_)                                             \
      _Pragma("unroll")                                                        \
      for (int ks_ = 0; ks_ < 2; ++ks_)                                        \
        acc[(mh) * 4 + i_][(nh) * 2 + j_] = __builtin_amdgcn_mfma_f32_16x16x32_bf16( \
            aA[i_][ks_], arr[j_][ks_], acc[(mh) * 4 + i_][(nh) * 2 + j_], 0, 0, 0); \
  __builtin_amdgcn_s_setprio(0);                                               \
  tail;                                                                        \
  __builtin_amdgcn_s_barrier();                                                \
} while (0)

template<bool OUT_BF16, bool ROPE>
__global__ __launch_bounds__(512, 2) void gemm256(const unsigned short* __restrict__ A,
                                                  const unsigned short* __restrict__ B,
                                                  void* __restrict__ Cv,
                                                  int M, int N, int K,
                                                  const float* __restrict__ fc,
                                                  const float* __restrict__ fs){
  __shared__ char LDS[131072];
  const int tid = threadIdx.x;
  const int l = tid & 63, w = tid >> 6;
  const int lq = l & 15, lg = l >> 4;
  const int wm = w >> 2, wn = w & 3;

  const int cpx = gridDim.x >> 3;
  const int orig = blockIdx.x;
  const int sw = (orig & 7) * cpx + (orig >> 3);
  const int nbc = N >> 8;
  const int br = sw / nbc, bc = sw % nbc;

  f32x4 acc[8][4] = {};
  bf16x8 aA[4][2], bB0[2][2], bB1[2][2];
  const unsigned short* Ag = A + (size_t)br * 256 * K;
  const unsigned short* Bg = B + (size_t)bc * 256 * K;
  const int NT = K >> 6;

  STAGE(0, Ag, 0, 0, 0); STAGE(1, Bg, 0, 0, 0);
  STAGE(0, Ag, 1, 0, 0); STAGE(1, Bg, 1, 0, 0);
  STAGE(1, Bg, 0, 1, 1); STAGE(0, Ag, 0, 1, 1);
  asm volatile("s_waitcnt vmcnt(4)" ::: "memory");
  __builtin_amdgcn_s_barrier();

  for (int t = 0; t < NT; ++t){
    const int par = t & 1, parn = par ^ 1;
    RD_A(BUF(0, 0, par));
    RD_B(BUF(1, 0, par), bB0);
    if (t + 1 < NT) STAGE(0, Ag, 1, parn, t + 1);
    DO_MFMA(0, 0, bB0, (void)0);
    RD_B(BUF(1, 1, par), bB1);
    if (t + 1 < NT) STAGE(1, Bg, 1, parn, t + 1);
    DO_MFMA(0, 1, bB1, (void)0);
    RD_A(BUF(0, 1, par));
    if (t + 2 < NT) STAGE(0, Ag, 0, par, t + 2);
    DO_MFMA(1, 0, bB0, (void)0);
    if (t + 2 < NT) STAGE(1, Bg, 0, par, t + 2);
    DO_MFMA(1, 1, bB1, asm volatile("s_waitcnt vmcnt(4)" ::: "memory"));
  }

#pragma unroll
  for (int i = 0; i < 8; ++i){
    int grow = br * 256 + (i >> 2) * 128 + wm * 64 + (i & 3) * 16 + lg * 4;
#pragma unroll
    for (int j = 0; j < 4; ++j){
      int gcol = bc * 256 + (j >> 1) * 128 + wn * 32 + (j & 1) * 16 + lq;
#pragma unroll
      for (int r = 0; r < 4; ++r){
        float v = acc[i][j][r];
        if (ROPE){
          int s = (grow + r) & 2047;
          int i0 = (gcol & 127) >> 1;
          float cc = fc[s * 64 + i0], sn = fs[s * 64 + i0];
          float part = __shfl_xor(v, 1, 64);
          v = (lq & 1) ? __builtin_fmaf(part, sn, v * cc)
                       : __builtin_fmaf(-part, sn, v * cc);
        }
        if (OUT_BF16)
          ((unsigned short*)Cv)[(size_t)(grow + r) * N + gcol] = f2bf(v);
        else
          ((float*)Cv)[(size_t)(grow + r) * N + gcol] = v;
      }
    }
  }
}

// ---------------- Flash attention (causal), swapped-QK^T, 8 waves, dbuf ----------------
// No online-max: Q pre-scaled by log2e/sqrt(d); p = exp2(s); final 1/lrow normalize.
__global__ __launch_bounds__(512, 2) void attn_fwd(const unsigned short* __restrict__ Q,
                                                   const unsigned short* __restrict__ K,
                                                   const unsigned short* __restrict__ V,
                                                   unsigned short* __restrict__ O){
  __shared__ unsigned short SMEM[2 * 64 * 128 + 2 * 128 * 64];   // 64 KB
  unsigned short* Ks = SMEM;
  unsigned short* Vt = SMEM + 16384;

  const int tid = threadIdx.x;
  const int l = tid & 63, wid = tid >> 6;
  const int lq = l & 31, hi = l >> 5;
  const int bh = blockIdx.x & 63;
  const int tsel = blockIdx.x >> 8;
  const int kidx = (blockIdx.x >> 6) & 3;
  const int qt = tsel ? kidx : 7 - kidx;          // pairs (i,i+256): (7,0),(6,1),(5,2),(4,3)
  const int b = bh >> 4, h = bh & 15;
  const int qw = qt * 256 + wid * 32;
  const float c2 = 0.12751743f;                   // (1/sqrt(128)) * log2(e)

  const unsigned short* qptr = Q + ((size_t)(b * 2048 + qw + lq)) * 2048 + (size_t)h * 128;
  bf16x8 qf[8];
#pragma unroll
  for (int ks = 0; ks < 8; ++ks){
    u16x8 qr = *(const u16x8*)(qptr + ks * 16 + hi * 8);
    union { unsigned u[4]; bf16x8 v; } qq;
#pragma unroll
    for (int e = 0; e < 4; ++e)
      qq.u[e] = cvtpk(bf2f(qr[2 * e]) * c2, bf2f(qr[2 * e + 1]) * c2);
    qf[ks] = qq.v;
  }

  f32x16 oacc[4];
#pragma unroll
  for (int i = 0; i < 4; ++i)
#pragma unroll
    for (int j = 0; j < 16; ++j) oacc[i][j] = 0.f;
  float lrow = 0.f;

  const int dblk = tid >> 5, kvp = tid & 31;
  const size_t hb = (size_t)b * 2048 * 2048 + (size_t)h * 128;
  u16x8 r0, r1;

  {
    const size_t kvb = hb;
#pragma unroll
    for (int c = 0; c < 2; ++c){
      int off = c * 8192 + tid * 16;
      int row = off >> 8, colb = off & 255;
      gload_lds16((const char*)(K + kvb + (size_t)row * 2048) + (colb ^ ((row & 15) << 4)),
                  (char*)Ks + c * 8192 + (tid >> 6) * 1024 + (tid & 63) * 16);
    }
    const unsigned short* vp = V + kvb + (size_t)(2 * kvp) * 2048 + dblk * 8;
    r0 = *(const u16x8*)vp; r1 = *(const u16x8*)(vp + 2048);
    asm volatile("s_waitcnt vmcnt(0)" ::: "memory");
#pragma unroll
    for (int j = 0; j < 8; ++j){
      int d = dblk * 8 + j;
      unsigned val = (unsigned)r0[j] | ((unsigned)r1[j] << 16);
      *(unsigned*)((char*)Vt + d * 128 + ((4 * kvp) ^ vswz(d))) = val;
    }
  }
  __syncthreads();

  const int nkt = 4 * qt + 4;
  for (int kt = 0; kt < nkt; ++kt){
    const int cur = kt & 1, nxt = cur ^ 1;
    const bool pref = (kt + 1 < nkt);
    char* KsC = (char*)(Ks + cur * 8192);
    char* VtC = (char*)(Vt + cur * 8192);

    if (pref){
      const size_t kvb = hb + (size_t)((kt + 1) * 64) * 2048;
      char* KsN = (char*)(Ks + nxt * 8192);
#pragma unroll
      for (int c = 0; c < 2; ++c){
        int off = c * 8192 + tid * 16;
        int row = off >> 8, colb = off & 255;
        gload_lds16((const char*)(K + kvb + (size_t)row * 2048) + (colb ^ ((row & 15) << 4)),
                    KsN + c * 8192 + (tid >> 6) * 1024 + (tid & 63) * 16);
      }
      const unsigned short* vp = V + kvb + (size_t)(2 * kvp) * 2048 + dblk * 8;
      r0 = *(const u16x8*)vp; r1 = *(const u16x8*)(vp + 2048);
    }

    if (!(kt * 64 > qw + 31)){
      f32x16 sacc[2];
#pragma unroll
      for (int sub = 0; sub < 2; ++sub){
#pragma unroll
        for (int j = 0; j < 16; ++j) sacc[sub][j] = 0.f;
        const int row = sub * 32 + lq;
        const int swz = (row & 15) << 4;
#pragma unroll
        for (int ks = 0; ks < 8; ++ks){
          bf16x8 kf = *(const bf16x8*)(KsC + row * 256 + ((ks * 32 + hi * 16) ^ swz));
          sacc[sub] = __builtin_amdgcn_mfma_f32_32x32x16_bf16(kf, qf[ks], sacc[sub], 0, 0, 0);
        }
      }

      float s[32];
#pragma unroll
      for (int sub = 0; sub < 2; ++sub)
#pragma unroll
        for (int r = 0; r < 16; ++r) s[sub * 16 + r] = sacc[sub][r];

      if (kt * 64 + 63 > qw){
        const int qg = qw + lq;
#pragma unroll
        for (int sub = 0; sub < 2; ++sub)
#pragma unroll
          for (int r = 0; r < 16; ++r){
            int kvg = kt * 64 + sub * 32 + (r & 3) + 8 * (r >> 2) + 4 * hi;
            if (kvg > qg) s[sub * 16 + r] = -3.0e38f;
          }
      }

      float p[32];
#pragma unroll
      for (int i = 0; i < 32; ++i)
        p[i] = __builtin_amdgcn_exp2f(s[i]);
      float sm[32];
#pragma unroll
      for (int i = 0; i < 32; ++i) sm[i] = p[i];
#pragma unroll
      for (int st = 1; st < 32; st <<= 1)
#pragma unroll
        for (int i = 0; i < 32; i += 2 * st) sm[i] += sm[i + st];
      lrow += xsum32(sm[0]);

      unsigned wv[16];
#pragma unroll
      for (int i = 0; i < 16; ++i) wv[i] = cvtpk(p[2 * i], p[2 * i + 1]);
      swap32(wv[0], wv[2]);   swap32(wv[1], wv[3]);
      swap32(wv[4], wv[6]);   swap32(wv[5], wv[7]);
      swap32(wv[8], wv[10]);  swap32(wv[9], wv[11]);
      swap32(wv[12], wv[14]); swap32(wv[13], wv[15]);

#pragma unroll
      for (int c = 0; c < 4; ++c){
        union { unsigned u[4]; bf16x8 v; } pu;
        pu.u[0] = wv[c * 4 + 0]; pu.u[1] = wv[c * 4 + 1];
        pu.u[2] = wv[c * 4 + 2]; pu.u[3] = wv[c * 4 + 3];
#pragma unroll
        for (int db = 0; db < 4; ++db){
          const int d = db * 32 + lq;
          bf16x8 vf = *(const bf16x8*)(VtC + d * 128 + ((c * 32 + hi * 16) ^ vswz(d)));
          oacc[db] = __builtin_amdgcn_mfma_f32_32x32x16_bf16(vf, pu.v, oacc[db], 0, 0, 0);
        }
      }
    }

    if (pref){
      asm volatile("s_waitcnt vmcnt(0)" ::: "memory");
      char* VtN = (char*)(Vt + nxt * 8192);
#pragma unroll
      for (int j = 0; j < 8; ++j){
        int d = dblk * 8 + j;
        unsigned val = (unsigned)r0[j] | ((unsigned)r1[j] << 16);
        *(unsigned*)(VtN + d * 128 + ((4 * kvp) ^ vswz(d))) = val;
      }
    }
    __syncthreads();
  }

  float inv = 1.0f / lrow;
  char* lb = (char*)SMEM + wid * 8192;
#pragma unroll
  for (int db = 0; db < 4; ++db)
#pragma unroll
    for (int r = 0; r < 16; r += 2){
      int d = db * 32 + (r & 3) + 8 * (r >> 2) + 4 * hi;
      unsigned val = (unsigned)f2bf(oacc[db][r] * inv) |
                     ((unsigned)f2bf(oacc[db][r + 1] * inv) << 16);
      *(unsigned*)(lb + lq * 256 + ((2 * d) ^ ((lq & 7) << 4))) = val;
    }
  __syncthreads();
#pragma unroll
  for (int i = 0; i < 8; ++i){
    int rowq = i * 4 + (l >> 4);
    u16x8 vv = *(const u16x8*)(lb + rowq * 256 + (((l & 15) * 16) ^ ((rowq & 7) << 4)));
    *(u16x8*)(O + ((size_t)(b * 2048 + qw + rowq)) * 2048 + (size_t)h * 128 + (l & 15) * 8) = vv;
  }
}

// ---------------- host-side launch ----------------
extern "C" void kernel_launch(void* const* d_in, const int* in_sizes, int n_in,
                              void* d_out, int out_size, void* d_ws, size_t ws_size,
                              hipStream_t stream){
  const float* x  = (const float*)d_in[0];
  const float* wq = (const float*)d_in[1];
  const float* wk = (const float*)d_in[2];
  const float* wv = (const float*)d_in[3];
  const float* wo = (const float*)d_in[4];
  const float* fc = (const float*)d_in[5];
  const float* fs = (const float*)d_in[6];
  float* out = (float*)d_out;
  (void)in_sizes; (void)n_in; (void)out_size; (void)ws_size;

  const size_t XN = (size_t)8192 * 2048;
  const size_t WN = (size_t)2048 * 2048;

  unsigned short* xb  = (unsigned short*)d_ws;
  unsigned short* wqb = xb + XN;
  unsigned short* wkb = wqb + WN;
  unsigned short* wvb = wkb + WN;
  unsigned short* wob = wvb + WN;
  unsigned short* q   = wob + WN;
  unsigned short* k   = q + XN;
  unsigned short* v   = k + XN;
  unsigned short* att = xb;                // alias: x-bf16 dead after QKV GEMMs

  cvt_all<<<dim3(32768), 256, 0, stream>>>(x, wq, wk, wv, wo, xb, wqb, wkb, wvb, wob);

  gemm256<true, true ><<<dim3(256), 512, 0, stream>>>(xb, wqb, q, 8192, 2048, 2048, fc, fs);
  gemm256<true, true ><<<dim3(256), 512, 0, stream>>>(xb, wkb, k, 8192, 2048, 2048, fc, fs);
  gemm256<true, false><<<dim3(256), 512, 0, stream>>>(xb, wvb, v, 8192, 2048, 2048, nullptr, nullptr);

  attn_fwd<<<dim3(512), 512, 0, stream>>>(q, k, v, att);

  gemm256<false, false><<<dim3(256), 512, 0, stream>>>(att, wob, out, 8192, 2048, 2048,
                                                       nullptr, nullptr);
}

// Round 14
// 374.136 us; speedup vs baseline: 1.3209x; 1.0222x over previous
//
#include <hip/hip_runtime.h>

typedef __attribute__((ext_vector_type(8))) __bf16 bf16x8;
typedef __attribute__((ext_vector_type(4))) float f32x4;
typedef __attribute__((ext_vector_type(16))) float f32x16;
typedef __attribute__((ext_vector_type(8))) unsigned short u16x8;
typedef __attribute__((ext_vector_type(2))) unsigned uint2v;

__device__ __forceinline__ unsigned short f2bf(float f){
  union { float f; unsigned u; } v; v.f = f;
  unsigned r = v.u + 0x7FFFu + ((v.u >> 16) & 1u);
  return (unsigned short)(r >> 16);
}
__device__ __forceinline__ float bf2f(unsigned short u){
  union { unsigned u; float f; } v; v.u = ((unsigned)u) << 16;
  return v.f;
}

typedef const unsigned __attribute__((address_space(1)))* gas_ptr;
typedef unsigned __attribute__((address_space(3)))* las_ptr;

__device__ __forceinline__ void gload_lds16(const void* g, void* l){
  __builtin_amdgcn_global_load_lds((gas_ptr)g, (las_ptr)l, 16, 0, 0);
}

__device__ __forceinline__ unsigned cvtpk(float lo, float hi){
  unsigned r;
  asm("v_cvt_pk_bf16_f32 %0, %1, %2" : "=v"(r) : "v"(lo), "v"(hi));
  return r;
}
__device__ __forceinline__ void swap32(unsigned &a, unsigned &b){
  uint2v r = __builtin_amdgcn_permlane32_swap(a, b, false, false);
  a = r[0]; b = r[1];
}
__device__ __forceinline__ float xsum32(float v){
  union { float f; unsigned u; } a; a.f = v;
  uint2v r = __builtin_amdgcn_permlane32_swap(a.u, a.u, false, false);
  union { unsigned u; float f; } x, y; x.u = r[0]; y.u = r[1];
  return x.f + y.f;
}

// Vt swizzle (R13-verified): row-closed, bijective, PV lane quad -> 4 distinct chunks
__device__ __forceinline__ int vswz(int d){
  return ((d & 7) ^ ((d >> 3) & 3)) << 4;
}

// ---------------- f32 -> bf16 conversion: x + 4 weights, one dispatch ----------------
__global__ __launch_bounds__(256) void cvt_all(const float* __restrict__ x,
                                               const float* __restrict__ w0, const float* __restrict__ w1,
                                               const float* __restrict__ w2, const float* __restrict__ w3,
                                               unsigned short* __restrict__ xb,
                                               unsigned short* o0, unsigned short* o1,
                                               unsigned short* o2, unsigned short* o3){
  int bid = blockIdx.x;
  const float* in; unsigned short* out; size_t base;
  if (bid < 16384){ in = x; out = xb; base = (size_t)bid * 1024; }
  else {
    int r = bid - 16384, sel = r >> 12;
    in  = sel == 0 ? w0 : sel == 1 ? w1 : sel == 2 ? w2 : w3;
    out = sel == 0 ? o0 : sel == 1 ? o1 : sel == 2 ? o2 : o3;
    base = (size_t)(r & 4095) * 1024;
  }
  size_t i = base + (size_t)threadIdx.x * 4;
  float4 vv = *(const float4*)(in + i);
  ushort4 o;
  o.x = f2bf(vv.x); o.y = f2bf(vv.y); o.z = f2bf(vv.z); o.w = f2bf(vv.w);
  *(ushort4*)(out + i) = o;
}

// ============ 256x256 GEMM, 16x16x32 MFMA, 4-phase, reg-cached ============
// R13 + (a) no forced lgkmcnt(0) -- compiler emits fine-grained waits for C++
// ds_reads; (b) ONE barrier per phase (closing only) -- WAR separation >= 2
// closing barriers verified per buffer; boundary vmcnt(4) unchanged.
#define BUF(op, half, par) (LDS + (((op) * 2 + (half)) * 2 + (par)) * 16384)

#define STAGE(op, gbase, half, par, kt) do {                                   \
  _Pragma("unroll")                                                            \
  for (int c_ = 0; c_ < 2; ++c_){                                              \
    int slot_ = c_ * 512 + w * 64 + l;                                         \
    int row_ = slot_ >> 3, colb_ = slot_ & 7;                                  \
    gload_lds16((const char*)((gbase) + (size_t)((half) * 128 + row_) * K +    \
                              (size_t)(kt) * 64 + ((colb_ ^ (row_ & 7)) * 8)), \
                BUF(op, half, par) + c_ * 8192 + w * 1024);                    \
  } } while (0)

#define RD_A(buf) do {                                                         \
  const char* Ab_ = (buf);                                                     \
  _Pragma("unroll")                                                            \
  for (int i_ = 0; i_ < 4; ++i_){                                              \
    int row_ = wm * 64 + i_ * 16 + lq;                                         \
    _Pragma("unroll")                                                          \
    for (int ks_ = 0; ks_ < 2; ++ks_)                                          \
      aA[i_][ks_] = *(const bf16x8*)(Ab_ + row_ * 128 +                        \
                                     (((ks_ * 4 + lg) ^ (row_ & 7)) * 16));    \
  } } while (0)

#define RD_B(buf, arr) do {                                                    \
  const char* Bb_ = (buf);                                                     \
  _Pragma("unroll")                                                            \
  for (int j_ = 0; j_ < 2; ++j_){                                              \
    int row_ = wn * 32 + j_ * 16 + lq;                                         \
    _Pragma("unroll")                                                          \
    for (int ks_ = 0; ks_ < 2; ++ks_)                                          \
      arr[j_][ks_] = *(const bf16x8*)(Bb_ + row_ * 128 +                       \
                                      (((ks_ * 4 + lg) ^ (row_ & 7)) * 16));   \
  } } while (0)

#define DO_MFMA(mh, nh, arr, tail) do {                                        \
  __builtin_amdgcn_s_setprio(1);                                               \
  _Pragma("unroll")                                                            \
  for (int i_ = 0; i_ < 4; ++i_)                                               \
    _Pragma("unroll")                                                          \
    for (int j_ = 0; j_ < 2; ++j_)                                             \
      _Pragma("unroll")                                                        \
      for (int ks_ = 0; ks_ < 2; ++ks_)                                        \
        acc[(mh) * 4 + i_][(nh) * 2 + j_] = __builtin_amdgcn_mfma_f32_16x16x32_bf16( \
            aA[i_][ks_], arr[j_][ks_], acc[(mh) * 4 + i_][(nh) * 2 + j_], 0, 0, 0); \
  __builtin_amdgcn_s_setprio(0);                                               \
  tail;                                                                        \
  __builtin_amdgcn_s_barrier();                                                \
} while (0)

template<bool OUT_BF16, bool ROPE>
__global__ __launch_bounds__(512, 2) void gemm256(const unsigned short* __restrict__ A,
                                                  const unsigned short* __restrict__ B,
                                                  void* __restrict__ Cv,
                                                  int M, int N, int K,
                                                  const float* __restrict__ fc,
                                                  const float* __restrict__ fs){
  __shared__ char LDS[131072];
  const int tid = threadIdx.x;
  const int l = tid & 63, w = tid >> 6;
  const int lq = l & 15, lg = l >> 4;
  const int wm = w >> 2, wn = w & 3;

  const int cpx = gridDim.x >> 3;
  const int orig = blockIdx.x;
  const int sw = (orig & 7) * cpx + (orig >> 3);
  const int nbc = N >> 8;
  const int br = sw / nbc, bc = sw % nbc;

  f32x4 acc[8][4] = {};
  bf16x8 aA[4][2], bB0[2][2], bB1[2][2];
  const unsigned short* Ag = A + (size_t)br * 256 * K;
  const unsigned short* Bg = B + (size_t)bc * 256 * K;
  const int NT = K >> 6;

  STAGE(0, Ag, 0, 0, 0); STAGE(1, Bg, 0, 0, 0);
  STAGE(0, Ag, 1, 0, 0); STAGE(1, Bg, 1, 0, 0);
  STAGE(1, Bg, 0, 1, 1); STAGE(0, Ag, 0, 1, 1);
  asm volatile("s_waitcnt vmcnt(4)" ::: "memory");
  __builtin_amdgcn_s_barrier();

  for (int t = 0; t < NT; ++t){
    const int par = t & 1, parn = par ^ 1;
    RD_A(BUF(0, 0, par));
    RD_B(BUF(1, 0, par), bB0);
    if (t + 1 < NT) STAGE(0, Ag, 1, parn, t + 1);
    DO_MFMA(0, 0, bB0, (void)0);
    RD_B(BUF(1, 1, par), bB1);
    if (t + 1 < NT) STAGE(1, Bg, 1, parn, t + 1);
    DO_MFMA(0, 1, bB1, (void)0);
    RD_A(BUF(0, 1, par));
    if (t + 2 < NT) STAGE(0, Ag, 0, par, t + 2);
    DO_MFMA(1, 0, bB0, (void)0);
    if (t + 2 < NT) STAGE(1, Bg, 0, par, t + 2);
    DO_MFMA(1, 1, bB1, asm volatile("s_waitcnt vmcnt(4)" ::: "memory"));
  }

#pragma unroll
  for (int i = 0; i < 8; ++i){
    int grow = br * 256 + (i >> 2) * 128 + wm * 64 + (i & 3) * 16 + lg * 4;
#pragma unroll
    for (int j = 0; j < 4; ++j){
      int gcol = bc * 256 + (j >> 1) * 128 + wn * 32 + (j & 1) * 16 + lq;
#pragma unroll
      for (int r = 0; r < 4; ++r){
        float v = acc[i][j][r];
        if (ROPE){
          int s = (grow + r) & 2047;
          int i0 = (gcol & 127) >> 1;
          float cc = fc[s * 64 + i0], sn = fs[s * 64 + i0];
          float part = __shfl_xor(v, 1, 64);
          v = (lq & 1) ? __builtin_fmaf(part, sn, v * cc)
                       : __builtin_fmaf(-part, sn, v * cc);
        }
        if (OUT_BF16)
          ((unsigned short*)Cv)[(size_t)(grow + r) * N + gcol] = f2bf(v);
        else
          ((float*)Cv)[(size_t)(grow + r) * N + gcol] = v;
      }
    }
  }
}

// ---------------- Flash attention (causal), swapped-QK^T, 8 waves, dbuf ----------------
// No online-max: Q pre-scaled by log2e/sqrt(d); p = exp2(s); final 1/lrow normalize.
// Prefetch order: V reg-loads FIRST, K gloads after -> V-pack (compiler-waited at
// vmcnt(2)-equivalent) overlaps K-gload tail; vmcnt(0) only before the barrier.
__global__ __launch_bounds__(512, 2) void attn_fwd(const unsigned short* __restrict__ Q,
                                                   const unsigned short* __restrict__ K,
                                                   const unsigned short* __restrict__ V,
                                                   unsigned short* __restrict__ O){
  __shared__ unsigned short SMEM[2 * 64 * 128 + 2 * 128 * 64];   // 64 KB
  unsigned short* Ks = SMEM;
  unsigned short* Vt = SMEM + 16384;

  const int tid = threadIdx.x;
  const int l = tid & 63, wid = tid >> 6;
  const int lq = l & 31, hi = l >> 5;
  const int bh = blockIdx.x & 63;
  const int tsel = blockIdx.x >> 8;
  const int kidx = (blockIdx.x >> 6) & 3;
  const int qt = tsel ? kidx : 7 - kidx;          // pairs (i,i+256): (7,0),(6,1),(5,2),(4,3)
  const int b = bh >> 4, h = bh & 15;
  const int qw = qt * 256 + wid * 32;
  const float c2 = 0.12751743f;                   // (1/sqrt(128)) * log2(e)

  const unsigned short* qptr = Q + ((size_t)(b * 2048 + qw + lq)) * 2048 + (size_t)h * 128;
  bf16x8 qf[8];
#pragma unroll
  for (int ks = 0; ks < 8; ++ks){
    u16x8 qr = *(const u16x8*)(qptr + ks * 16 + hi * 8);
    union { unsigned u[4]; bf16x8 v; } qq;
#pragma unroll
    for (int e = 0; e < 4; ++e)
      qq.u[e] = cvtpk(bf2f(qr[2 * e]) * c2, bf2f(qr[2 * e + 1]) * c2);
    qf[ks] = qq.v;
  }

  f32x16 oacc[4];
#pragma unroll
  for (int i = 0; i < 4; ++i)
#pragma unroll
    for (int j = 0; j < 16; ++j) oacc[i][j] = 0.f;
  float lrow = 0.f;

  const int dblk = tid >> 5, kvp = tid & 31;
  const size_t hb = (size_t)b * 2048 * 2048 + (size_t)h * 128;
  u16x8 r0, r1;

  {
    const size_t kvb = hb;
    const unsigned short* vp = V + kvb + (size_t)(2 * kvp) * 2048 + dblk * 8;
    r0 = *(const u16x8*)vp; r1 = *(const u16x8*)(vp + 2048);
#pragma unroll
    for (int c = 0; c < 2; ++c){
      int off = c * 8192 + tid * 16;
      int row = off >> 8, colb = off & 255;
      gload_lds16((const char*)(K + kvb + (size_t)row * 2048) + (colb ^ ((row & 15) << 4)),
                  (char*)Ks + c * 8192 + (tid >> 6) * 1024 + (tid & 63) * 16);
    }
#pragma unroll
    for (int j = 0; j < 8; ++j){
      int d = dblk * 8 + j;
      unsigned val = (unsigned)r0[j] | ((unsigned)r1[j] << 16);
      *(unsigned*)((char*)Vt + d * 128 + ((4 * kvp) ^ vswz(d))) = val;
    }
    asm volatile("s_waitcnt vmcnt(0)" ::: "memory");
  }
  __syncthreads();

  const int nkt = 4 * qt + 4;
  for (int kt = 0; kt < nkt; ++kt){
    const int cur = kt & 1, nxt = cur ^ 1;
    const bool pref = (kt + 1 < nkt);
    char* KsC = (char*)(Ks + cur * 8192);
    char* VtC = (char*)(Vt + cur * 8192);

    if (pref){
      const size_t kvb = hb + (size_t)((kt + 1) * 64) * 2048;
      const unsigned short* vp = V + kvb + (size_t)(2 * kvp) * 2048 + dblk * 8;
      r0 = *(const u16x8*)vp; r1 = *(const u16x8*)(vp + 2048);
      char* KsN = (char*)(Ks + nxt * 8192);
#pragma unroll
      for (int c = 0; c < 2; ++c){
        int off = c * 8192 + tid * 16;
        int row = off >> 8, colb = off & 255;
        gload_lds16((const char*)(K + kvb + (size_t)row * 2048) + (colb ^ ((row & 15) << 4)),
                    KsN + c * 8192 + (tid >> 6) * 1024 + (tid & 63) * 16);
      }
    }

    if (!(kt * 64 > qw + 31)){
      f32x16 sacc[2];
#pragma unroll
      for (int sub = 0; sub < 2; ++sub){
#pragma unroll
        for (int j = 0; j < 16; ++j) sacc[sub][j] = 0.f;
        const int row = sub * 32 + lq;
        const int swz = (row & 15) << 4;
#pragma unroll
        for (int ks = 0; ks < 8; ++ks){
          bf16x8 kf = *(const bf16x8*)(KsC + row * 256 + ((ks * 32 + hi * 16) ^ swz));
          sacc[sub] = __builtin_amdgcn_mfma_f32_32x32x16_bf16(kf, qf[ks], sacc[sub], 0, 0, 0);
        }
      }

      float s[32];
#pragma unroll
      for (int sub = 0; sub < 2; ++sub)
#pragma unroll
        for (int r = 0; r < 16; ++r) s[sub * 16 + r] = sacc[sub][r];

      if (kt * 64 + 63 > qw){
        const int qg = qw + lq;
#pragma unroll
        for (int sub = 0; sub < 2; ++sub)
#pragma unroll
          for (int r = 0; r < 16; ++r){
            int kvg = kt * 64 + sub * 32 + (r & 3) + 8 * (r >> 2) + 4 * hi;
            if (kvg > qg) s[sub * 16 + r] = -3.0e38f;
          }
      }

      float p[32];
#pragma unroll
      for (int i = 0; i < 32; ++i)
        p[i] = __builtin_amdgcn_exp2f(s[i]);
      float sm[32];
#pragma unroll
      for (int i = 0; i < 32; ++i) sm[i] = p[i];
#pragma unroll
      for (int st = 1; st < 32; st <<= 1)
#pragma unroll
        for (int i = 0; i < 32; i += 2 * st) sm[i] += sm[i + st];
      lrow += xsum32(sm[0]);

      unsigned wv[16];
#pragma unroll
      for (int i = 0; i < 16; ++i) wv[i] = cvtpk(p[2 * i], p[2 * i + 1]);
      swap32(wv[0], wv[2]);   swap32(wv[1], wv[3]);
      swap32(wv[4], wv[6]);   swap32(wv[5], wv[7]);
      swap32(wv[8], wv[10]);  swap32(wv[9], wv[11]);
      swap32(wv[12], wv[14]); swap32(wv[13], wv[15]);

#pragma unroll
      for (int c = 0; c < 4; ++c){
        union { unsigned u[4]; bf16x8 v; } pu;
        pu.u[0] = wv[c * 4 + 0]; pu.u[1] = wv[c * 4 + 1];
        pu.u[2] = wv[c * 4 + 2]; pu.u[3] = wv[c * 4 + 3];
#pragma unroll
        for (int db = 0; db < 4; ++db){
          const int d = db * 32 + lq;
          bf16x8 vf = *(const bf16x8*)(VtC + d * 128 + ((c * 32 + hi * 16) ^ vswz(d)));
          oacc[db] = __builtin_amdgcn_mfma_f32_32x32x16_bf16(vf, pu.v, oacc[db], 0, 0, 0);
        }
      }
    }

    if (pref){
      char* VtN = (char*)(Vt + nxt * 8192);
#pragma unroll
      for (int j = 0; j < 8; ++j){
        int d = dblk * 8 + j;
        unsigned val = (unsigned)r0[j] | ((unsigned)r1[j] << 16);
        *(unsigned*)(VtN + d * 128 + ((4 * kvp) ^ vswz(d))) = val;
      }
      asm volatile("s_waitcnt vmcnt(0)" ::: "memory");
    }
    __syncthreads();
  }

  float inv = 1.0f / lrow;
  char* lb = (char*)SMEM + wid * 8192;
#pragma unroll
  for (int db = 0; db < 4; ++db)
#pragma unroll
    for (int r = 0; r < 16; r += 2){
      int d = db * 32 + (r & 3) + 8 * (r >> 2) + 4 * hi;
      unsigned val = (unsigned)f2bf(oacc[db][r] * inv) |
                     ((unsigned)f2bf(oacc[db][r + 1] * inv) << 16);
      *(unsigned*)(lb + lq * 256 + ((2 * d) ^ ((lq & 7) << 4))) = val;
    }
  __syncthreads();
#pragma unroll
  for (int i = 0; i < 8; ++i){
    int rowq = i * 4 + (l >> 4);
    u16x8 vv = *(const u16x8*)(lb + rowq * 256 + (((l & 15) * 16) ^ ((rowq & 7) << 4)));
    *(u16x8*)(O + ((size_t)(b * 2048 + qw + rowq)) * 2048 + (size_t)h * 128 + (l & 15) * 8) = vv;
  }
}

// ---------------- host-side launch ----------------
extern "C" void kernel_launch(void* const* d_in, const int* in_sizes, int n_in,
                              void* d_out, int out_size, void* d_ws, size_t ws_size,
                              hipStream_t stream){
  const float* x  = (const float*)d_in[0];
  const float* wq = (const float*)d_in[1];
  const float* wk = (const float*)d_in[2];
  const float* wv = (const float*)d_in[3];
  const float* wo = (const float*)d_in[4];
  const float* fc = (const float*)d_in[5];
  const float* fs = (const float*)d_in[6];
  float* out = (float*)d_out;
  (void)in_sizes; (void)n_in; (void)out_size; (void)ws_size;

  const size_t XN = (size_t)8192 * 2048;
  const size_t WN = (size_t)2048 * 2048;

  unsigned short* xb  = (unsigned short*)d_ws;
  unsigned short* wqb = xb + XN;
  unsigned short* wkb = wqb + WN;
  unsigned short* wvb = wkb + WN;
  unsigned short* wob = wvb + WN;
  unsigned short* q   = wob + WN;
  unsigned short* k   = q + XN;
  unsigned short* v   = k + XN;
  unsigned short* att = xb;                // alias: x-bf16 dead after QKV GEMMs

  cvt_all<<<dim3(32768), 256, 0, stream>>>(x, wq, wk, wv, wo, xb, wqb, wkb, wvb, wob);

  gemm256<true, true ><<<dim3(256), 512, 0, stream>>>(xb, wqb, q, 8192, 2048, 2048, fc, fs);
  gemm256<true, true ><<<dim3(256), 512, 0, stream>>>(xb, wkb, k, 8192, 2048, 2048, fc, fs);
  gemm256<true, false><<<dim3(256), 512, 0, stream>>>(xb, wvb, v, 8192, 2048, 2048, nullptr, nullptr);

  attn_fwd<<<dim3(512), 512, 0, stream>>>(q, k, v, att);

  gemm256<false, false><<<dim3(256), 512, 0, stream>>>(att, wob, out, 8192, 2048, 2048,
                                                       nullptr, nullptr);
}